// Round 7
// baseline (1250.302 us; speedup 1.0000x reference)
//
#include <hip/hip_runtime.h>
#include <stdint.h>
#include <math.h>

// ---------- types ----------
typedef __attribute__((ext_vector_type(8))) short bf16x8;   // 8 bf16 (4 VGPR)
typedef __attribute__((ext_vector_type(4))) short bf16x4;
typedef __attribute__((ext_vector_type(4))) float f32x4;

__device__ __forceinline__ short f2bf(float f) {
  unsigned u = __builtin_bit_cast(unsigned, f);
  unsigned r = u + 0x7fffu + ((u >> 16) & 1u);
  return (short)(r >> 16);
}

__device__ __forceinline__ f32x4 mfma16(bf16x8 a, bf16x8 b, f32x4 c) {
  return __builtin_amdgcn_mfma_f32_16x16x32_bf16(a, b, c, 0, 0, 0);
}

// async global->LDS, 16B per lane. LDS dest = wave-uniform base + lane*16.
__device__ __forceinline__ void gload16(const void* g, void* l) {
  __builtin_amdgcn_global_load_lds((const __attribute__((address_space(1))) void*)g,
                                   (__attribute__((address_space(3))) void*)l, 16, 0, 0);
}

// LDS tile index: row-major [rows][64] bf16, 16B-chunk XOR swizzle on row&7.
__device__ __forceinline__ int swz(int row, int col) {
  return row * 64 + (((col >> 3) ^ (row & 7)) << 3) + (col & 7);
}

// ---------- embedding (4 rows/block, wave per row) ----------
__global__ __launch_bounds__(256) void embed_k(const int* __restrict__ ids,
                                               const float* __restrict__ tok,
                                               const float* __restrict__ pos,
                                               float* __restrict__ x) {
  const int t = threadIdx.x, w = t >> 6, lane = t & 63;
  const int row = blockIdx.x * 4 + w;
  const int id = ids[row];
#pragma unroll
  for (int i = 0; i < 4; ++i) {
    const int c = (i * 64 + lane) * 4;
    const float4 a = *reinterpret_cast<const float4*>(tok + (size_t)id * 1024 + c);
    const float4 b = *reinterpret_cast<const float4*>(pos + (size_t)row * 1024 + c);
    float4 o = make_float4(a.x + b.x, a.y + b.y, a.z + b.z, a.w + b.w);
    *reinterpret_cast<float4*>(x + (size_t)row * 1024 + c) = o;
  }
}

// ---------- layernorm (wave per row, 4 rows/block, no LDS/barrier) ----------
__global__ __launch_bounds__(256) void ln_k(const float* __restrict__ x,
                                            const float* __restrict__ gw,
                                            const float* __restrict__ bw,
                                            short* __restrict__ out) {
  const int t = threadIdx.x, w = t >> 6, lane = t & 63;
  const int row = blockIdx.x * 4 + w;
  float4 v[4];
  float s = 0.f, q = 0.f;
#pragma unroll
  for (int i = 0; i < 4; ++i) {
    v[i] = *reinterpret_cast<const float4*>(x + (size_t)row * 1024 + (i * 64 + lane) * 4);
    s += v[i].x + v[i].y + v[i].z + v[i].w;
    q += v[i].x * v[i].x + v[i].y * v[i].y + v[i].z * v[i].z + v[i].w * v[i].w;
  }
#pragma unroll
  for (int o = 32; o > 0; o >>= 1) { s += __shfl_xor(s, o); q += __shfl_xor(q, o); }
  const float mean = s * (1.f / 1024.f);
  const float var  = q * (1.f / 1024.f) - mean * mean;
  const float rstd = rsqrtf(var + 1e-5f);
#pragma unroll
  for (int i = 0; i < 4; ++i) {
    const int c = (i * 64 + lane) * 4;
    const float4 gv = *reinterpret_cast<const float4*>(gw + c);
    const float4 bv = *reinterpret_cast<const float4*>(bw + c);
    bf16x4 ov = { f2bf((v[i].x - mean) * rstd * gv.x + bv.x),
                  f2bf((v[i].y - mean) * rstd * gv.y + bv.y),
                  f2bf((v[i].z - mean) * rstd * gv.z + bv.z),
                  f2bf((v[i].w - mean) * rstd * gv.w + bv.w) };
    *reinterpret_cast<bf16x4*>(out + (size_t)row * 1024 + c) = ov;
  }
}

// ---------- weight transpose + f32->bf16 convert ----------
__global__ __launch_bounds__(256) void tcvt_k(const float* __restrict__ W,
                                              short* __restrict__ Wt,
                                              int N, size_t inStride, size_t outStride,
                                              int rowOff, int ldOut, float scale) {
  __shared__ float T[128][68];
  const float* Win = W + blockIdx.z * inStride;
  short* Wout = Wt + blockIdx.z * outStride;
  const int n0 = blockIdx.x * 64, k0 = blockIdx.y * 128;
  const int t = threadIdx.x;
  const int nc = (t & 15) * 4, kr = t >> 4;
#pragma unroll
  for (int p = 0; p < 8; ++p) {
    const float4 v = *reinterpret_cast<const float4*>(Win + (size_t)(k0 + kr + 16 * p) * N + n0 + nc);
    T[kr + 16 * p][nc + 0] = v.x;
    T[kr + 16 * p][nc + 1] = v.y;
    T[kr + 16 * p][nc + 2] = v.z;
    T[kr + 16 * p][nc + 3] = v.w;
  }
  __syncthreads();
  const int n = t >> 2, ks = (t & 3) * 32;
  short tmp[32];
#pragma unroll
  for (int i = 0; i < 32; ++i) tmp[i] = f2bf(T[ks + i][n] * scale);
  short* op = Wout + (size_t)(rowOff + n0 + n) * ldOut + k0 + ks;
#pragma unroll
  for (int c = 0; c < 4; ++c)
    *reinterpret_cast<bf16x8*>(op + c * 8) = *reinterpret_cast<bf16x8*>(tmp + c * 8);
}

// concat qkv bias (q scaled by 0.125)
__global__ __launch_bounds__(256) void bqkv_k(const float* __restrict__ qb,
                                              const float* __restrict__ kb,
                                              const float* __restrict__ vb,
                                              float* __restrict__ o) {
  int l = blockIdx.y;
  int c = blockIdx.x * 256 + threadIdx.x;
  float v;
  if (c < 1024) v = qb[l * 1024 + c] * 0.125f;
  else if (c < 1280) v = kb[l * 256 + c - 1024];
  else v = vb[l * 256 + c - 1280];
  o[l * 1536 + c] = v;
}

// ---------- V transpose (fallback path only) ----------
__global__ __launch_bounds__(256) void vtr_k(const short* __restrict__ v, int vld,
                                             short* __restrict__ vt) {
  __shared__ short T[64][80];
  const int kvh = blockIdx.y;
  const int s0 = blockIdx.x * 64;
  const int t = threadIdx.x;
  const int row = t >> 3, ch = t & 7;
#pragma unroll
  for (int p = 0; p < 2; ++p) {
    int s = row + 32 * p;
    bf16x8 vv = *reinterpret_cast<const bf16x8*>(v + (size_t)(s0 + s) * vld + kvh * 64 + ch * 8);
    *reinterpret_cast<bf16x8*>(&T[s][ch * 8]) = vv;
  }
  __syncthreads();
#pragma unroll
  for (int p = 0; p < 2; ++p) {
    int d = row + 32 * p;
    short tmp[8];
#pragma unroll
    for (int i = 0; i < 8; ++i) tmp[i] = T[ch * 8 + i][d];
    *reinterpret_cast<bf16x8*>(vt + (size_t)(kvh * 64 + d) * 2048 + s0 + ch * 8) =
        *reinterpret_cast<bf16x8*>(tmp);
  }
}

// ---------- 256x256 8-wave phase-split GEMM (head): C = A @ Wt^T, f32 out ----------
// 512 threads (8 waves, 2M x 4N), BK=64, LDS 128 KB double-buffered.
// Per K-tile: 4 phases (C-quadrants), 16 MFMA each, raw s_barrier between phases,
// setprio around MFMA; staging for tile t+1 issued phases 0-1; vmcnt(0)+barrier at
// tile boundary only.
__global__ __launch_bounds__(512, 2)
void gemm_h8(const short* __restrict__ A, const short* __restrict__ Wt,
             float* __restrict__ out, int M, int N, int K) {
  __shared__ short As[2][256 * 64];
  __shared__ short Bs[2][256 * 64];
  const int t = threadIdx.x;
  const int lane = t & 63, w = t >> 6;
  const int g = lane >> 4, r = lane & 15;
  const int wm = w >> 2, wn = w & 3;

  int bx = blockIdx.x, by = blockIdx.y;
  {  // bijective m-fastest XCD chunking (nwg=1000, %8==0)
    const int nbx = gridDim.x, nby = gridDim.y, nwg = nbx * nby;
    const int bid = by * nbx + bx;
    const int q = nwg >> 3, rr = nwg & 7;
    const int xcd = bid & 7, loc = bid >> 3;
    const int sw = (xcd < rr ? xcd * (q + 1) : rr * (q + 1) + (xcd - rr) * q) + loc;
    by = sw % nby; bx = sw / nby;
  }
  const int m0 = by * 256, n0 = bx * 256;

  f32x4 acc[8][4];
#pragma unroll
  for (int i = 0; i < 8; ++i)
#pragma unroll
    for (int j = 0; j < 4; ++j) { f32x4 z = {0.f, 0.f, 0.f, 0.f}; acc[i][j] = z; }

  const int srow8 = lane >> 3, sslot = lane & 7;
  const int NTILES = K >> 6;

  // prologue: stage tile 0 into buf 0 (4 rounds x {A,B})
#pragma unroll
  for (int rnd = 0; rnd < 4; ++rnd) {
    const int row = rnd * 64 + w * 8 + srow8;
    const int col = (sslot ^ (row & 7)) << 3;
    gload16(A + (size_t)(m0 + row) * K + col, &As[0][(rnd * 64 + w * 8) * 64]);
    gload16(Wt + (size_t)(n0 + row) * K + col, &Bs[0][(rnd * 64 + w * 8) * 64]);
  }
  asm volatile("s_waitcnt vmcnt(0)" ::: "memory");
  __builtin_amdgcn_s_barrier();
  __builtin_amdgcn_sched_barrier(0);

  for (int tt = 0; tt < NTILES; ++tt) {
    const int cur = tt & 1;
    const short* Ac = As[cur];
    const short* Bc = Bs[cur];
    short* An = &As[cur ^ 1][0];
    short* Bn = &Bs[cur ^ 1][0];
    const bool pref = (tt + 1 < NTILES);
    const int k1 = (tt + 1) << 6;

#pragma unroll
    for (int q = 0; q < 4; ++q) {
      const int qm = q >> 1, qn = q & 1;
      // stage next tile: rounds 2q,2q+1 during phases 0-1 (4 gloads each)
      if (q < 2 && pref) {
#pragma unroll
        for (int h = 0; h < 2; ++h) {
          const int rnd = 2 * q + h;
          const int row = rnd * 64 + w * 8 + srow8;
          const int col = (sslot ^ (row & 7)) << 3;
          gload16(A + (size_t)(m0 + row) * K + k1 + col, &An[(rnd * 64 + w * 8) * 64]);
          gload16(Wt + (size_t)(n0 + row) * K + k1 + col, &Bn[(rnd * 64 + w * 8) * 64]);
        }
      }
      // ds_read quadrant fragments (wave-local; compiler tracks deps)
      bf16x8 af[2][4], bfr[2][2];
#pragma unroll
      for (int kk = 0; kk < 2; ++kk) {
#pragma unroll
        for (int mt = 0; mt < 4; ++mt)
          af[kk][mt] = *reinterpret_cast<const bf16x8*>(
              &Ac[swz(wm * 128 + qm * 64 + mt * 16 + r, kk * 32 + g * 8)]);
#pragma unroll
        for (int nt = 0; nt < 2; ++nt)
          bfr[kk][nt] = *reinterpret_cast<const bf16x8*>(
              &Bc[swz(wn * 64 + qn * 32 + nt * 16 + r, kk * 32 + g * 8)]);
      }
      __builtin_amdgcn_s_barrier();   // phase lockstep (no implicit drain)
      __builtin_amdgcn_s_setprio(1);
#pragma unroll
      for (int kk = 0; kk < 2; ++kk)
#pragma unroll
        for (int mt = 0; mt < 4; ++mt)
#pragma unroll
          for (int nt = 0; nt < 2; ++nt)
            acc[qm * 4 + mt][qn * 2 + nt] =
                mfma16(af[kk][mt], bfr[kk][nt], acc[qm * 4 + mt][qn * 2 + nt]);
      __builtin_amdgcn_s_setprio(0);
      if (q == 3) {  // tile boundary: next tile's stages must be landed for all waves
        asm volatile("s_waitcnt vmcnt(0)" ::: "memory");
      }
      __builtin_amdgcn_s_barrier();
      if (q == 3) __builtin_amdgcn_sched_barrier(0);
    }
  }
  // epilogue: C[row, col], row = m0+wm*128+mi*16+4g+j, col = n0+wn*64+ni*16+r
#pragma unroll
  for (int mi = 0; mi < 8; ++mi) {
    const int row = m0 + wm * 128 + mi * 16 + 4 * g;
#pragma unroll
    for (int ni = 0; ni < 4; ++ni) {
      const int col = n0 + wn * 64 + ni * 16 + r;
#pragma unroll
      for (int j = 0; j < 4; ++j)
        out[(size_t)(row + j) * N + col] = acc[mi][ni][j];
    }
  }
}

// ---------- GEMM (m97 structure): C[M,N] = A_bf16[M,K] @ Wt_bf16[N,K]^T ----------
// EPI: 0 bf16 out (acc+bias); 1 bf16 GELU(acc+bias); 2 f32 resid+acc+bias;
//      3 f32 acc; 4 = EPI0 + transposed-V store (cols>=1280 -> vt[(col-1280)][row], bf16x4)
// XSWZ: 0 identity; 1 m-fastest bijective XCD chunking (L2 W-panel reuse)
// TILE: 0 = 128x128; 1 = 128x64 (2x blocks, for N<=1536 or latency-bound GEMMs)
template <int EPI, int XSWZ, int TILE>
__global__ __launch_bounds__(256, 4)
void gemm_bt(const short* __restrict__ A, const short* __restrict__ Wt,
             const float* __restrict__ bias, const float* __restrict__ resid,
             void* __restrict__ out, int M, int N, int K, int nbOff,
             short* __restrict__ vt) {
  constexpr int BN   = (TILE == 0) ? 128 : 64;  // block n-extent
  constexpr int WN   = (TILE == 0) ? 64 : 32;   // wave n-extent
  constexpr int NT   = (TILE == 0) ? 4 : 2;     // n-frags per wave
  constexpr int BISS = (TILE == 0) ? 4 : 2;     // B staging issues per wave
  __shared__ short As[128 * 64];
  __shared__ short Bs[BN * 64];
  const int t = threadIdx.x;
  const int lane = t & 63, w = t >> 6;
  const int g = lane >> 4, r = lane & 15;
  const int wr = w >> 1, wc = w & 1;

  int bx = blockIdx.x, by = blockIdx.y;
  if (XSWZ == 1) {
    const int nbx = gridDim.x, nby = gridDim.y, nwg = nbx * nby;
    const int bid = by * nbx + bx;
    const int q = nwg >> 3, rr = nwg & 7;
    const int xcd = bid & 7, loc = bid >> 3;
    const int sw = (xcd < rr ? xcd * (q + 1) : rr * (q + 1) + (xcd - rr) * q) + loc;
    by = sw % nby; bx = sw / nby;  // m-fastest: XCD-contiguous blocks share an n-panel
  }
  const int m0 = by * 128, n0 = (bx + nbOff) * BN;

  f32x4 acc[4][NT];
#pragma unroll
  for (int i = 0; i < 4; ++i)
#pragma unroll
    for (int j = 0; j < NT; ++j) { f32x4 z = {0.f, 0.f, 0.f, 0.f}; acc[i][j] = z; }

  const int srow = lane >> 3, sslot = lane & 7;

  for (int k0 = 0; k0 < K; k0 += 64) {
#pragma unroll
    for (int i = 0; i < 4; ++i) {
      const int rowA = w * 32 + i * 8 + srow;
      const int colA = (sslot ^ (srow & 7)) << 3;
      gload16(A + (size_t)(m0 + rowA) * K + k0 + colA, &As[(w * 32 + i * 8) * 64]);
    }
#pragma unroll
    for (int i = 0; i < BISS; ++i) {
      const int rowB = w * (8 * BISS) + i * 8 + srow;
      const int colB = (sslot ^ (srow & 7)) << 3;
      gload16(Wt + (size_t)(n0 + rowB) * K + k0 + colB, &Bs[(w * (8 * BISS) + i * 8) * 64]);
    }
    __syncthreads();
#pragma unroll
    for (int kk = 0; kk < 64; kk += 32) {
      bf16x8 af[4], bfg[NT];
#pragma unroll
      for (int mt = 0; mt < 4; ++mt)
        af[mt] = *reinterpret_cast<const bf16x8*>(&As[swz(wr * 64 + mt * 16 + r, kk + g * 8)]);
#pragma unroll
      for (int nt = 0; nt < NT; ++nt)
        bfg[nt] = *reinterpret_cast<const bf16x8*>(&Bs[swz(wc * WN + nt * 16 + r, kk + g * 8)]);
#pragma unroll
      for (int mt = 0; mt < 4; ++mt)
#pragma unroll
        for (int nt = 0; nt < NT; ++nt)
          acc[mt][nt] = mfma16(af[mt], bfg[nt], acc[mt][nt]);
    }
    __syncthreads();
  }
#pragma unroll
  for (int nt = 0; nt < NT; ++nt) {
    const int col = n0 + wc * WN + nt * 16 + r;
    const float bv = (EPI == 3) ? 0.f : bias[col];
#pragma unroll
    for (int mt = 0; mt < 4; ++mt) {
      const int rowb = m0 + wr * 64 + mt * 16 + 4 * g;
      short vs[4];
#pragma unroll
      for (int j = 0; j < 4; ++j) {
        const int row = rowb + j;
        const size_t oi = (size_t)row * N + col;
        float vv = acc[mt][nt][j] + bv;
        if (EPI == 0) {
          ((short*)out)[oi] = f2bf(vv);
        } else if (EPI == 1) {
          vv = 0.5f * vv * (1.f + erff(vv * 0.70710678118654752f));
          ((short*)out)[oi] = f2bf(vv);
        } else if (EPI == 2) {
          ((float*)out)[oi] = resid[oi] + vv;
        } else if (EPI == 3) {
          ((float*)out)[oi] = vv;
        } else {  // EPI 4
          short bb = f2bf(vv);
          ((short*)out)[oi] = bb;
          vs[j] = bb;
        }
      }
      if (EPI == 4 && col >= 1280) {
        bf16x4 pk = { vs[0], vs[1], vs[2], vs[3] };
        *reinterpret_cast<bf16x4*>(vt + (size_t)(col - 1280) * 2048 + rowb) = pk;
      }
    }
  }
}

// ---------- legacy GEMM (f32 weights) — fallback if ws too small ----------
template <int EPI>
__global__ __launch_bounds__(256)
void gemm_k(const short* __restrict__ A, const float* __restrict__ W,
            const float* __restrict__ bias, const float* resid, void* out,
            int M, int N, int K, float scale) {
  __shared__ short As[128 * 64];
  __shared__ short Bs[128 * 64];
  const int t = threadIdx.x;
  const int lane = t & 63;
  const int g = lane >> 4, r = lane & 15;
  const int wid = t >> 6, wr = wid >> 1, wc = wid & 1;
  const int m0 = blockIdx.y * 128, n0 = blockIdx.x * 128;
  f32x4 acc[4][4];
#pragma unroll
  for (int i = 0; i < 4; ++i)
#pragma unroll
    for (int j = 0; j < 4; ++j) { f32x4 z = {0.f, 0.f, 0.f, 0.f}; acc[i][j] = z; }
  const int arow = t >> 3, ac = t & 7;
  const int bnn = t >> 1, bkh = t & 1;
  for (int k0 = 0; k0 < K; k0 += 64) {
#pragma unroll
    for (int p = 0; p < 4; ++p) {
      int row = arow + 32 * p;
      bf16x8 av = *reinterpret_cast<const bf16x8*>(A + (size_t)(m0 + row) * K + k0 + ac * 8);
      *reinterpret_cast<bf16x8*>(&As[swz(row, ac * 8)]) = av;
    }
#pragma unroll
    for (int p = 0; p < 8; ++p) {
      int kg = 4 * (bkh + 2 * p);
      const float* wp = W + (size_t)(k0 + kg) * N + n0 + bnn;
      bf16x4 wv = { f2bf(wp[0]), f2bf(wp[(size_t)N]), f2bf(wp[(size_t)2 * N]), f2bf(wp[(size_t)3 * N]) };
      *reinterpret_cast<bf16x4*>(&Bs[swz(bnn, kg)]) = wv;
    }
    __syncthreads();
#pragma unroll
    for (int kk = 0; kk < 64; kk += 32) {
      bf16x8 af[4], bfg[4];
#pragma unroll
      for (int mt = 0; mt < 4; ++mt)
        af[mt] = *reinterpret_cast<const bf16x8*>(&As[swz(wr * 64 + mt * 16 + r, kk + g * 8)]);
#pragma unroll
      for (int nt = 0; nt < 4; ++nt)
        bfg[nt] = *reinterpret_cast<const bf16x8*>(&Bs[swz(wc * 64 + nt * 16 + r, kk + g * 8)]);
#pragma unroll
      for (int mt = 0; mt < 4; ++mt)
#pragma unroll
        for (int nt = 0; nt < 4; ++nt)
          acc[mt][nt] = mfma16(af[mt], bfg[nt], acc[mt][nt]);
    }
    __syncthreads();
  }
#pragma unroll
  for (int nt = 0; nt < 4; ++nt) {
    const int col = n0 + wc * 64 + nt * 16 + r;
    const float bv = (EPI == 3) ? 0.f : bias[col];
#pragma unroll
    for (int mt = 0; mt < 4; ++mt) {
#pragma unroll
      for (int j = 0; j < 4; ++j) {
        const int row = m0 + wr * 64 + mt * 16 + 4 * g + j;
        const size_t oi = (size_t)row * N + col;
        float vv = acc[mt][nt][j] + bv;
        if (EPI == 0) {
          ((short*)out)[oi] = f2bf(vv * scale);
        } else if (EPI == 1) {
          vv = 0.5f * vv * (1.f + erff(vv * 0.70710678118654752f));
          ((short*)out)[oi] = f2bf(vv);
        } else if (EPI == 2) {
          ((float*)out)[oi] = resid[oi] + vv;
        } else {
          ((float*)out)[oi] = vv;
        }
      }
    }
  }
}

// ---------- flash-style GQA attention (dbuf, gload_lds staging) ----------
__global__ __launch_bounds__(256) void attn_k(const short* __restrict__ q, int qld,
                                              const short* __restrict__ k, int kld,
                                              const short* __restrict__ vt,
                                              const float* __restrict__ mask,
                                              short* __restrict__ o) {
  __shared__ short Ks[2][64 * 64];  // [s][d], 16B-chunk swizzled
  __shared__ short Vs[2][64 * 64];  // [d][s], 16B-chunk swizzled
  const int t = threadIdx.x, lane = t & 63, w = t >> 6;
  const int g = lane >> 4, r = lane & 15;
  const int h = blockIdx.y, qb = blockIdx.x, kvh = h >> 2;
  const int qrow = qb * 64 + w * 16 + r;

  const short* qp = q + (size_t)qrow * qld + h * 64;
  bf16x8 qf0 = *reinterpret_cast<const bf16x8*>(qp + g * 8);
  bf16x8 qf1 = *reinterpret_cast<const bf16x8*>(qp + 32 + g * 8);

  const short* kbase = k + kvh * 64;                   // + s*kld
  const short* vbase = vt + (size_t)kvh * 64 * 2048;   // + d*2048 + s

  f32x4 oacc[4];
#pragma unroll
  for (int i = 0; i < 4; ++i) { f32x4 z = {0.f, 0.f, 0.f, 0.f}; oacc[i] = z; }
  float m_run = -INFINITY, l_run = 0.f;

  const int srow = w * 8 + (lane >> 3), schunk = lane & 7;

#pragma unroll
  for (int p = 0; p < 2; ++p) {
    const int rr = srow + 32 * p;
    const int cc = (schunk ^ (rr & 7)) << 3;
    gload16(kbase + (size_t)rr * kld + cc, (char*)Ks + p * 4096 + w * 1024);
    gload16(vbase + (size_t)rr * 2048 + cc, (char*)Vs + p * 4096 + w * 1024);
  }
  asm volatile("s_waitcnt vmcnt(0)" ::: "memory");
  __syncthreads();

  for (int it = 0; it < 32; ++it) {
    const int cur = it & 1;
    if (it < 31) {
      const int s1 = (it + 1) * 64;
#pragma unroll
      for (int p = 0; p < 2; ++p) {
        const int rr = srow + 32 * p;
        const int cc = (schunk ^ (rr & 7)) << 3;
        gload16(kbase + (size_t)(s1 + rr) * kld + cc,
                (char*)Ks + (cur ^ 1) * 8192 + p * 4096 + w * 1024);
        gload16(vbase + (size_t)rr * 2048 + s1 + cc,
                (char*)Vs + (cur ^ 1) * 8192 + p * 4096 + w * 1024);
      }
    }
    const int s0 = it * 64;
    const short* Kc = Ks[cur];
    const short* Vc = Vs[cur];

    f32x4 sa[4];
#pragma unroll
    for (int st = 0; st < 4; ++st) {
      bf16x8 kf0 = *reinterpret_cast<const bf16x8*>(&Kc[swz(st * 16 + r, g * 8)]);
      bf16x8 kf1 = *reinterpret_cast<const bf16x8*>(&Kc[swz(st * 16 + r, 32 + g * 8)]);
      f32x4 z = {0.f, 0.f, 0.f, 0.f};
      z = mfma16(kf0, qf0, z);
      z = mfma16(kf1, qf1, z);
      sa[st] = z;
    }
    float sv[16];
    float pmax = -INFINITY;
#pragma unroll
    for (int st = 0; st < 4; ++st) {
      const float4 mv = *reinterpret_cast<const float4*>(mask + s0 + st * 16 + 4 * g);
#pragma unroll
      for (int j = 0; j < 4; ++j) {
        float xx = sa[st][j] + ((const float*)&mv)[j];
        sv[st * 4 + j] = xx;
        pmax = fmaxf(pmax, xx);
      }
    }
    pmax = fmaxf(pmax, __shfl_xor(pmax, 16));
    pmax = fmaxf(pmax, __shfl_xor(pmax, 32));
    float m_new = fmaxf(m_run, pmax);
    float corr = __expf(m_run - m_new);
    float psum = 0.f;
    short pb[16];
#pragma unroll
    for (int i = 0; i < 16; ++i) {
      float p = __expf(sv[i] - m_new);
      psum += p;
      pb[i] = f2bf(p);
    }
    psum += __shfl_xor(psum, 16);
    psum += __shfl_xor(psum, 32);
    l_run = l_run * corr + psum;
    m_run = m_new;
#pragma unroll
    for (int dt = 0; dt < 4; ++dt)
#pragma unroll
      for (int j = 0; j < 4; ++j) oacc[dt][j] *= corr;

#pragma unroll
    for (int hs = 0; hs < 2; ++hs) {
      bf16x8 pf = { pb[hs * 8 + 0], pb[hs * 8 + 1], pb[hs * 8 + 2], pb[hs * 8 + 3],
                    pb[hs * 8 + 4], pb[hs * 8 + 5], pb[hs * 8 + 6], pb[hs * 8 + 7] };
#pragma unroll
      for (int dt = 0; dt < 4; ++dt) {
        int d = dt * 16 + r;
        int c1 = 4 * g + 32 * hs;
        bf16x4 va  = *reinterpret_cast<const bf16x4*>(&Vc[swz(d, c1)]);
        bf16x4 vb2 = *reinterpret_cast<const bf16x4*>(&Vc[swz(d, c1 + 16)]);
        bf16x8 vf = { va[0], va[1], va[2], va[3], vb2[0], vb2[1], vb2[2], vb2[3] };
        oacc[dt] = mfma16(vf, pf, oacc[dt]);
      }
    }
    asm volatile("s_waitcnt vmcnt(0)" ::: "memory");
    __syncthreads();
  }
  float inv = 1.f / l_run;
#pragma unroll
  for (int dt = 0; dt < 4; ++dt) {
    bf16x4 ov = { f2bf(oacc[dt][0] * inv), f2bf(oacc[dt][1] * inv),
                  f2bf(oacc[dt][2] * inv), f2bf(oacc[dt][3] * inv) };
    *reinterpret_cast<bf16x4*>(o + (size_t)qrow * 1024 + h * 64 + dt * 16 + 4 * g) = ov;
  }
}

// ---------- launch ----------
extern "C" void kernel_launch(void* const* d_in, const int* in_sizes, int n_in,
                              void* d_out, int out_size, void* d_ws, size_t ws_size,
                              hipStream_t stream) {
  const int*   ids   = (const int*)d_in[0];
  const float* mask  = (const float*)d_in[1];
  const float* tok   = (const float*)d_in[2];
  const float* pos   = (const float*)d_in[3];
  const float* qW    = (const float*)d_in[4];
  const float* qbias = (const float*)d_in[5];
  const float* kW    = (const float*)d_in[6];
  const float* kbias = (const float*)d_in[7];
  const float* vW    = (const float*)d_in[8];
  const float* vbias = (const float*)d_in[9];
  const float* oW    = (const float*)d_in[10];
  const float* obias = (const float*)d_in[11];
  const float* m1W   = (const float*)d_in[12];
  const float* m1b   = (const float*)d_in[13];
  const float* m2W   = (const float*)d_in[14];
  const float* m2b   = (const float*)d_in[15];
  const float* ln1g  = (const float*)d_in[16];
  const float* ln1b  = (const float*)d_in[17];
  const float* ln2g  = (const float*)d_in[18];
  const float* ln2b  = (const float*)d_in[19];
  const float* lnfg  = (const float*)d_in[20];
  const float* lnfb  = (const float*)d_in[21];
  const float* headW = (const float*)d_in[22];
  float* out = (float*)d_out;

  char* ws = (char*)d_ws;
  float* x   = (float*)ws;                        // 8 MB
  short* xb  = (short*)(ws + 8388608ull);         // 4 MB

  const size_t OFF_QKV  = 12582912ull;   // 6 MB  bf16 [2048][1536]
  const size_t OFF_AO   = 18874368ull;   // 4 MB
  const size_t OFF_FF   = 23068672ull;   // 16 MB (first 1 MB aliased as vt between QKV-GEMM and attn)
  const size_t OFF_BQ   = 39845888ull;   // 24 KB f32 [4][1536]
  const size_t OFF_WQKV = 39870464ull;   // 12 MB bf16 [4][1536][1024]
  const size_t OFF_WO   = 52453376ull;   // 8 MB  bf16 [4][1024][1024]
  const size_t OFF_WM1  = 60841984ull;   // 32 MB bf16 [4][4096][1024]
  const size_t OFF_WM2  = 94396416ull;   // 32 MB bf16 [4][1024][4096]
  const size_t OFF_WH   = 127950848ull;  // 64 MB bf16 [32000][1024]
  const size_t NEED     = 193486848ull;

  if (ws_size >= NEED) {
    short* qkv  = (short*)(ws + OFF_QKV);
    short* ao   = (short*)(ws + OFF_AO);
    short* ff   = (short*)(ws + OFF_FF);
    short* vt   = ff;  // alias: ff dead during QKV->attn window
    float* bqv  = (float*)(ws + OFF_BQ);
    short* Wqkv = (short*)(ws + OFF_WQKV);
    short* Wo   = (short*)(ws + OFF_WO);
    short* Wm1  = (short*)(ws + OFF_WM1);
    short* Wm2  = (short*)(ws + OFF_WM2);
    short* Wh   = (short*)(ws + OFF_WH);

    tcvt_k<<<dim3(16, 8, 4), 256, 0, stream>>>(qW, Wqkv, 1024, 1048576ull, 1572864ull, 0, 1024, 0.125f);
    tcvt_k<<<dim3(4, 8, 4),  256, 0, stream>>>(kW, Wqkv, 256,  262144ull,  1572864ull, 1024, 1024, 1.f);
    tcvt_k<<<dim3(4, 8, 4),  256, 0, stream>>>(vW, Wqkv, 256,  262144ull,  1572864ull, 1280, 1024, 1.f);
    tcvt_k<<<dim3(16, 8, 4), 256, 0, stream>>>(oW, Wo, 1024, 1048576ull, 1048576ull, 0, 1024, 1.f);
    tcvt_k<<<dim3(64, 8, 4), 256, 0, stream>>>(m1W, Wm1, 4096, 4194304ull, 4194304ull, 0, 1024, 1.f);
    tcvt_k<<<dim3(16, 32, 4), 256, 0, stream>>>(m2W, Wm2, 1024, 4194304ull, 4194304ull, 0, 4096, 1.f);
    tcvt_k<<<dim3(500, 8, 1), 256, 0, stream>>>(headW, Wh, 32000, 0ull, 0ull, 0, 1024, 1.f);
    bqkv_k<<<dim3(6, 4), 256, 0, stream>>>(qbias, kbias, vbias, bqv);

    embed_k<<<512, 256, 0, stream>>>(ids, tok, pos, x);

    for (int l = 0; l < 4; ++l) {
      short* Wq_l  = Wqkv + (size_t)l * 1536 * 1024;
      short* Wo_l  = Wo   + (size_t)l * 1024 * 1024;
      short* Wm1_l = Wm1  + (size_t)l * 4096 * 1024;
      short* Wm2_l = Wm2  + (size_t)l * 1024 * 4096;

      ln_k<<<512, 256, 0, stream>>>(x, ln1g + l * 1024, ln1b + l * 1024, xb);
      gemm_bt<4, 0, 1><<<dim3(24, 16), 256, 0, stream>>>(xb, Wq_l, bqv + l * 1536, nullptr,
                                                         qkv, 2048, 1536, 1024, 0, vt);
      attn_k<<<dim3(32, 16), 256, 0, stream>>>(qkv, 1536, qkv + 1024, 1536, vt, mask, ao);
      gemm_bt<2, 0, 1><<<dim3(16, 16), 256, 0, stream>>>(ao, Wo_l, obias + l * 1024, x,
                                                         x, 2048, 1024, 1024, 0, nullptr);
      ln_k<<<512, 256, 0, stream>>>(x, ln2g + l * 1024, ln2b + l * 1024, xb);
      gemm_bt<1, 1, 1><<<dim3(64, 16), 256, 0, stream>>>(xb, Wm1_l, m1b + l * 4096, nullptr,
                                                         ff, 2048, 4096, 1024, 0, nullptr);
      gemm_bt<2, 1, 1><<<dim3(16, 16), 256, 0, stream>>>(ff, Wm2_l, m2b + l * 1024, x,
                                                         x, 2048, 1024, 4096, 0, nullptr);
    }
    ln_k<<<512, 256, 0, stream>>>(x, lnfg, lnfb, xb);
    gemm_h8<<<dim3(125, 8), 512, 0, stream>>>(xb, Wh, out, 2048, 32000, 1024);
  } else {
    // fallback: f32-weight GEMMs, needs < 40 MB ws
    short* qbf = (short*)(ws + (12u << 20));
    short* kbf = (short*)(ws + (16u << 20));
    short* vbf = (short*)(ws + (17u << 20));
    short* ao  = (short*)(ws + (18u << 20));
    short* ff  = (short*)(ws + (22u << 20));
    short* vtf = (short*)(ws + (38u << 20));

    embed_k<<<512, 256, 0, stream>>>(ids, tok, pos, x);
    for (int l = 0; l < 4; ++l) {
      ln_k<<<512, 256, 0, stream>>>(x, ln1g + l * 1024, ln1b + l * 1024, xb);
      gemm_k<0><<<dim3(8, 16), 256, 0, stream>>>(xb, qW + (size_t)l * 1024 * 1024,
          qbias + l * 1024, nullptr, qbf, 2048, 1024, 1024, 0.125f);
      gemm_k<0><<<dim3(2, 16), 256, 0, stream>>>(xb, kW + (size_t)l * 1024 * 256,
          kbias + l * 256, nullptr, kbf, 2048, 256, 1024, 1.f);
      gemm_k<0><<<dim3(2, 16), 256, 0, stream>>>(xb, vW + (size_t)l * 1024 * 256,
          vbias + l * 256, nullptr, vbf, 2048, 256, 1024, 1.f);
      vtr_k<<<dim3(32, 4), 256, 0, stream>>>(vbf, 256, vtf);
      attn_k<<<dim3(32, 16), 256, 0, stream>>>(qbf, 1024, kbf, 256, vtf, mask, ao);
      gemm_k<2><<<dim3(8, 16), 256, 0, stream>>>(ao, oW + (size_t)l * 1024 * 1024,
          obias + l * 1024, x, x, 2048, 1024, 1024, 1.f);
      ln_k<<<512, 256, 0, stream>>>(x, ln2g + l * 1024, ln2b + l * 1024, xb);
      gemm_k<1><<<dim3(32, 16), 256, 0, stream>>>(xb, m1W + (size_t)l * 1024 * 4096,
          m1b + l * 4096, nullptr, ff, 2048, 4096, 1024, 1.f);
      gemm_k<2><<<dim3(8, 16), 256, 0, stream>>>(ff, m2W + (size_t)l * 4096 * 1024,
          m2b + l * 1024, x, x, 2048, 1024, 4096, 1.f);
    }
    ln_k<<<512, 256, 0, stream>>>(x, lnfg, lnfb, xb);
    gemm_k<3><<<dim3(250, 16), 256, 0, stream>>>(xb, headW, nullptr, nullptr, out,
        2048, 32000, 1024, 1.f);
  }
}

// Round 8
// 1166.440 us; speedup vs baseline: 1.0719x; 1.0719x over previous
//
#include <hip/hip_runtime.h>
#include <stdint.h>
#include <math.h>

// ---------- types ----------
typedef __attribute__((ext_vector_type(8))) short bf16x8;   // 8 bf16 (4 VGPR)
typedef __attribute__((ext_vector_type(4))) short bf16x4;
typedef __attribute__((ext_vector_type(4))) float f32x4;

__device__ __forceinline__ short f2bf(float f) {
  unsigned u = __builtin_bit_cast(unsigned, f);
  unsigned r = u + 0x7fffu + ((u >> 16) & 1u);
  return (short)(r >> 16);
}

__device__ __forceinline__ f32x4 mfma16(bf16x8 a, bf16x8 b, f32x4 c) {
  return __builtin_amdgcn_mfma_f32_16x16x32_bf16(a, b, c, 0, 0, 0);
}

// async global->LDS, 16B per lane. LDS dest = wave-uniform base + lane*16.
__device__ __forceinline__ void gload16(const void* g, void* l) {
  __builtin_amdgcn_global_load_lds((const __attribute__((address_space(1))) void*)g,
                                   (__attribute__((address_space(3))) void*)l, 16, 0, 0);
}

// LDS tile index: row-major [rows][64] bf16, 16B-chunk XOR swizzle on row&7.
__device__ __forceinline__ int swz(int row, int col) {
  return row * 64 + (((col >> 3) ^ (row & 7)) << 3) + (col & 7);
}

// ---------- embedding (4 rows/block, wave per row) ----------
__global__ __launch_bounds__(256) void embed_k(const int* __restrict__ ids,
                                               const float* __restrict__ tok,
                                               const float* __restrict__ pos,
                                               float* __restrict__ x) {
  const int t = threadIdx.x, w = t >> 6, lane = t & 63;
  const int row = blockIdx.x * 4 + w;
  const int id = ids[row];
#pragma unroll
  for (int i = 0; i < 4; ++i) {
    const int c = (i * 64 + lane) * 4;
    const float4 a = *reinterpret_cast<const float4*>(tok + (size_t)id * 1024 + c);
    const float4 b = *reinterpret_cast<const float4*>(pos + (size_t)row * 1024 + c);
    float4 o = make_float4(a.x + b.x, a.y + b.y, a.z + b.z, a.w + b.w);
    *reinterpret_cast<float4*>(x + (size_t)row * 1024 + c) = o;
  }
}

// ---------- layernorm (wave per row, 4 rows/block, no LDS/barrier) ----------
__global__ __launch_bounds__(256) void ln_k(const float* __restrict__ x,
                                            const float* __restrict__ gw,
                                            const float* __restrict__ bw,
                                            short* __restrict__ out) {
  const int t = threadIdx.x, w = t >> 6, lane = t & 63;
  const int row = blockIdx.x * 4 + w;
  float4 v[4];
  float s = 0.f, q = 0.f;
#pragma unroll
  for (int i = 0; i < 4; ++i) {
    v[i] = *reinterpret_cast<const float4*>(x + (size_t)row * 1024 + (i * 64 + lane) * 4);
    s += v[i].x + v[i].y + v[i].z + v[i].w;
    q += v[i].x * v[i].x + v[i].y * v[i].y + v[i].z * v[i].z + v[i].w * v[i].w;
  }
#pragma unroll
  for (int o = 32; o > 0; o >>= 1) { s += __shfl_xor(s, o); q += __shfl_xor(q, o); }
  const float mean = s * (1.f / 1024.f);
  const float var  = q * (1.f / 1024.f) - mean * mean;
  const float rstd = rsqrtf(var + 1e-5f);
#pragma unroll
  for (int i = 0; i < 4; ++i) {
    const int c = (i * 64 + lane) * 4;
    const float4 gv = *reinterpret_cast<const float4*>(gw + c);
    const float4 bv = *reinterpret_cast<const float4*>(bw + c);
    bf16x4 ov = { f2bf((v[i].x - mean) * rstd * gv.x + bv.x),
                  f2bf((v[i].y - mean) * rstd * gv.y + bv.y),
                  f2bf((v[i].z - mean) * rstd * gv.z + bv.z),
                  f2bf((v[i].w - mean) * rstd * gv.w + bv.w) };
    *reinterpret_cast<bf16x4*>(out + (size_t)row * 1024 + c) = ov;
  }
}

// ---------- weight transpose + f32->bf16 convert ----------
__global__ __launch_bounds__(256) void tcvt_k(const float* __restrict__ W,
                                              short* __restrict__ Wt,
                                              int N, size_t inStride, size_t outStride,
                                              int rowOff, int ldOut, float scale) {
  __shared__ float T[128][68];
  const float* Win = W + blockIdx.z * inStride;
  short* Wout = Wt + blockIdx.z * outStride;
  const int n0 = blockIdx.x * 64, k0 = blockIdx.y * 128;
  const int t = threadIdx.x;
  const int nc = (t & 15) * 4, kr = t >> 4;
#pragma unroll
  for (int p = 0; p < 8; ++p) {
    const float4 v = *reinterpret_cast<const float4*>(Win + (size_t)(k0 + kr + 16 * p) * N + n0 + nc);
    T[kr + 16 * p][nc + 0] = v.x;
    T[kr + 16 * p][nc + 1] = v.y;
    T[kr + 16 * p][nc + 2] = v.z;
    T[kr + 16 * p][nc + 3] = v.w;
  }
  __syncthreads();
  const int n = t >> 2, ks = (t & 3) * 32;
  short tmp[32];
#pragma unroll
  for (int i = 0; i < 32; ++i) tmp[i] = f2bf(T[ks + i][n] * scale);
  short* op = Wout + (size_t)(rowOff + n0 + n) * ldOut + k0 + ks;
#pragma unroll
  for (int c = 0; c < 4; ++c)
    *reinterpret_cast<bf16x8*>(op + c * 8) = *reinterpret_cast<bf16x8*>(tmp + c * 8);
}

// concat qkv bias (q scaled by 0.125)
__global__ __launch_bounds__(256) void bqkv_k(const float* __restrict__ qb,
                                              const float* __restrict__ kb,
                                              const float* __restrict__ vb,
                                              float* __restrict__ o) {
  int l = blockIdx.y;
  int c = blockIdx.x * 256 + threadIdx.x;
  float v;
  if (c < 1024) v = qb[l * 1024 + c] * 0.125f;
  else if (c < 1280) v = kb[l * 256 + c - 1024];
  else v = vb[l * 256 + c - 1280];
  o[l * 1536 + c] = v;
}

// ---------- V transpose (fallback path only) ----------
__global__ __launch_bounds__(256) void vtr_k(const short* __restrict__ v, int vld,
                                             short* __restrict__ vt) {
  __shared__ short T[64][80];
  const int kvh = blockIdx.y;
  const int s0 = blockIdx.x * 64;
  const int t = threadIdx.x;
  const int row = t >> 3, ch = t & 7;
#pragma unroll
  for (int p = 0; p < 2; ++p) {
    int s = row + 32 * p;
    bf16x8 vv = *reinterpret_cast<const bf16x8*>(v + (size_t)(s0 + s) * vld + kvh * 64 + ch * 8);
    *reinterpret_cast<bf16x8*>(&T[s][ch * 8]) = vv;
  }
  __syncthreads();
#pragma unroll
  for (int p = 0; p < 2; ++p) {
    int d = row + 32 * p;
    short tmp[8];
#pragma unroll
    for (int i = 0; i < 8; ++i) tmp[i] = T[ch * 8 + i][d];
    *reinterpret_cast<bf16x8*>(vt + (size_t)(kvh * 64 + d) * 2048 + s0 + ch * 8) =
        *reinterpret_cast<bf16x8*>(tmp);
  }
}

// ---------- GEMM (m97 structure): C[M,N] = A_bf16[M,K] @ Wt_bf16[N,K]^T ----------
// EPI: 0 bf16 out (acc+bias); 1 bf16 GELU(acc+bias); 2 f32 resid+acc+bias;
//      3 f32 acc; 4 = EPI0 + transposed-V store (cols>=1280 -> vt[(col-1280)][row], bf16x4)
// XSWZ: 0 identity; 1 m-fastest bijective XCD chunking (L2 W-panel reuse)
// TILE: 0 = 128x128; 1 = 128x64 (2x blocks, for N<=1536 or latency-bound GEMMs)
template <int EPI, int XSWZ, int TILE>
__global__ __launch_bounds__(256, 4)
void gemm_bt(const short* __restrict__ A, const short* __restrict__ Wt,
             const float* __restrict__ bias, const float* __restrict__ resid,
             void* __restrict__ out, int M, int N, int K, int nbOff,
             short* __restrict__ vt) {
  constexpr int BN   = (TILE == 0) ? 128 : 64;  // block n-extent
  constexpr int WN   = (TILE == 0) ? 64 : 32;   // wave n-extent
  constexpr int NT   = (TILE == 0) ? 4 : 2;     // n-frags per wave
  constexpr int BISS = (TILE == 0) ? 4 : 2;     // B staging issues per wave
  __shared__ short As[128 * 64];
  __shared__ short Bs[BN * 64];
  const int t = threadIdx.x;
  const int lane = t & 63, w = t >> 6;
  const int g = lane >> 4, r = lane & 15;
  const int wr = w >> 1, wc = w & 1;

  int bx = blockIdx.x, by = blockIdx.y;
  if (XSWZ == 1) {
    const int nbx = gridDim.x, nby = gridDim.y, nwg = nbx * nby;
    const int bid = by * nbx + bx;
    const int q = nwg >> 3, rr = nwg & 7;
    const int xcd = bid & 7, loc = bid >> 3;
    const int sw = (xcd < rr ? xcd * (q + 1) : rr * (q + 1) + (xcd - rr) * q) + loc;
    by = sw % nby; bx = sw / nby;  // m-fastest: XCD-contiguous blocks share an n-panel
  }
  const int m0 = by * 128, n0 = (bx + nbOff) * BN;

  f32x4 acc[4][NT];
#pragma unroll
  for (int i = 0; i < 4; ++i)
#pragma unroll
    for (int j = 0; j < NT; ++j) { f32x4 z = {0.f, 0.f, 0.f, 0.f}; acc[i][j] = z; }

  const int srow = lane >> 3, sslot = lane & 7;

  for (int k0 = 0; k0 < K; k0 += 64) {
#pragma unroll
    for (int i = 0; i < 4; ++i) {
      const int rowA = w * 32 + i * 8 + srow;
      const int colA = (sslot ^ (srow & 7)) << 3;
      gload16(A + (size_t)(m0 + rowA) * K + k0 + colA, &As[(w * 32 + i * 8) * 64]);
    }
#pragma unroll
    for (int i = 0; i < BISS; ++i) {
      const int rowB = w * (8 * BISS) + i * 8 + srow;
      const int colB = (sslot ^ (srow & 7)) << 3;
      gload16(Wt + (size_t)(n0 + rowB) * K + k0 + colB, &Bs[(w * (8 * BISS) + i * 8) * 64]);
    }
    __syncthreads();
#pragma unroll
    for (int kk = 0; kk < 64; kk += 32) {
      bf16x8 af[4], bfg[NT];
#pragma unroll
      for (int mt = 0; mt < 4; ++mt)
        af[mt] = *reinterpret_cast<const bf16x8*>(&As[swz(wr * 64 + mt * 16 + r, kk + g * 8)]);
#pragma unroll
      for (int nt = 0; nt < NT; ++nt)
        bfg[nt] = *reinterpret_cast<const bf16x8*>(&Bs[swz(wc * WN + nt * 16 + r, kk + g * 8)]);
#pragma unroll
      for (int mt = 0; mt < 4; ++mt)
#pragma unroll
        for (int nt = 0; nt < NT; ++nt)
          acc[mt][nt] = mfma16(af[mt], bfg[nt], acc[mt][nt]);
    }
    __syncthreads();
  }
#pragma unroll
  for (int nt = 0; nt < NT; ++nt) {
    const int col = n0 + wc * WN + nt * 16 + r;
    const float bv = (EPI == 3) ? 0.f : bias[col];
#pragma unroll
    for (int mt = 0; mt < 4; ++mt) {
      const int rowb = m0 + wr * 64 + mt * 16 + 4 * g;
      short vs[4];
#pragma unroll
      for (int j = 0; j < 4; ++j) {
        const int row = rowb + j;
        const size_t oi = (size_t)row * N + col;
        float vv = acc[mt][nt][j] + bv;
        if (EPI == 0) {
          ((short*)out)[oi] = f2bf(vv);
        } else if (EPI == 1) {
          vv = 0.5f * vv * (1.f + erff(vv * 0.70710678118654752f));
          ((short*)out)[oi] = f2bf(vv);
        } else if (EPI == 2) {
          ((float*)out)[oi] = resid[oi] + vv;
        } else if (EPI == 3) {
          ((float*)out)[oi] = vv;
        } else {  // EPI 4
          short bb = f2bf(vv);
          ((short*)out)[oi] = bb;
          vs[j] = bb;
        }
      }
      if (EPI == 4 && col >= 1280) {
        bf16x4 pk = { vs[0], vs[1], vs[2], vs[3] };
        *reinterpret_cast<bf16x4*>(vt + (size_t)(col - 1280) * 2048 + rowb) = pk;
      }
    }
  }
}

// ---------- legacy GEMM (f32 weights) — fallback if ws too small ----------
template <int EPI>
__global__ __launch_bounds__(256)
void gemm_k(const short* __restrict__ A, const float* __restrict__ W,
            const float* __restrict__ bias, const float* resid, void* out,
            int M, int N, int K, float scale) {
  __shared__ short As[128 * 64];
  __shared__ short Bs[128 * 64];
  const int t = threadIdx.x;
  const int lane = t & 63;
  const int g = lane >> 4, r = lane & 15;
  const int wid = t >> 6, wr = wid >> 1, wc = wid & 1;
  const int m0 = blockIdx.y * 128, n0 = blockIdx.x * 128;
  f32x4 acc[4][4];
#pragma unroll
  for (int i = 0; i < 4; ++i)
#pragma unroll
    for (int j = 0; j < 4; ++j) { f32x4 z = {0.f, 0.f, 0.f, 0.f}; acc[i][j] = z; }
  const int arow = t >> 3, ac = t & 7;
  const int bnn = t >> 1, bkh = t & 1;
  for (int k0 = 0; k0 < K; k0 += 64) {
#pragma unroll
    for (int p = 0; p < 4; ++p) {
      int row = arow + 32 * p;
      bf16x8 av = *reinterpret_cast<const bf16x8*>(A + (size_t)(m0 + row) * K + k0 + ac * 8);
      *reinterpret_cast<bf16x8*>(&As[swz(row, ac * 8)]) = av;
    }
#pragma unroll
    for (int p = 0; p < 8; ++p) {
      int kg = 4 * (bkh + 2 * p);
      const float* wp = W + (size_t)(k0 + kg) * N + n0 + bnn;
      bf16x4 wv = { f2bf(wp[0]), f2bf(wp[(size_t)N]), f2bf(wp[(size_t)2 * N]), f2bf(wp[(size_t)3 * N]) };
      *reinterpret_cast<bf16x4*>(&Bs[swz(bnn, kg)]) = wv;
    }
    __syncthreads();
#pragma unroll
    for (int kk = 0; kk < 64; kk += 32) {
      bf16x8 af[4], bfg[4];
#pragma unroll
      for (int mt = 0; mt < 4; ++mt)
        af[mt] = *reinterpret_cast<const bf16x8*>(&As[swz(wr * 64 + mt * 16 + r, kk + g * 8)]);
#pragma unroll
      for (int nt = 0; nt < 4; ++nt)
        bfg[nt] = *reinterpret_cast<const bf16x8*>(&Bs[swz(wc * 64 + nt * 16 + r, kk + g * 8)]);
#pragma unroll
      for (int mt = 0; mt < 4; ++mt)
#pragma unroll
        for (int nt = 0; nt < 4; ++nt)
          acc[mt][nt] = mfma16(af[mt], bfg[nt], acc[mt][nt]);
    }
    __syncthreads();
  }
#pragma unroll
  for (int nt = 0; nt < 4; ++nt) {
    const int col = n0 + wc * 64 + nt * 16 + r;
    const float bv = (EPI == 3) ? 0.f : bias[col];
#pragma unroll
    for (int mt = 0; mt < 4; ++mt) {
#pragma unroll
      for (int j = 0; j < 4; ++j) {
        const int row = m0 + wr * 64 + mt * 16 + 4 * g + j;
        const size_t oi = (size_t)row * N + col;
        float vv = acc[mt][nt][j] + bv;
        if (EPI == 0) {
          ((short*)out)[oi] = f2bf(vv * scale);
        } else if (EPI == 1) {
          vv = 0.5f * vv * (1.f + erff(vv * 0.70710678118654752f));
          ((short*)out)[oi] = f2bf(vv);
        } else if (EPI == 2) {
          ((float*)out)[oi] = resid[oi] + vv;
        } else {
          ((float*)out)[oi] = vv;
        }
      }
    }
  }
}

// ---------- flash-style GQA attention (dbuf, gload_lds staging) ----------
__global__ __launch_bounds__(256) void attn_k(const short* __restrict__ q, int qld,
                                              const short* __restrict__ k, int kld,
                                              const short* __restrict__ vt,
                                              const float* __restrict__ mask,
                                              short* __restrict__ o) {
  __shared__ short Ks[2][64 * 64];  // [s][d], 16B-chunk swizzled
  __shared__ short Vs[2][64 * 64];  // [d][s], 16B-chunk swizzled
  const int t = threadIdx.x, lane = t & 63, w = t >> 6;
  const int g = lane >> 4, r = lane & 15;
  const int h = blockIdx.y, qb = blockIdx.x, kvh = h >> 2;
  const int qrow = qb * 64 + w * 16 + r;

  const short* qp = q + (size_t)qrow * qld + h * 64;
  bf16x8 qf0 = *reinterpret_cast<const bf16x8*>(qp + g * 8);
  bf16x8 qf1 = *reinterpret_cast<const bf16x8*>(qp + 32 + g * 8);

  const short* kbase = k + kvh * 64;                   // + s*kld
  const short* vbase = vt + (size_t)kvh * 64 * 2048;   // + d*2048 + s

  f32x4 oacc[4];
#pragma unroll
  for (int i = 0; i < 4; ++i) { f32x4 z = {0.f, 0.f, 0.f, 0.f}; oacc[i] = z; }
  float m_run = -INFINITY, l_run = 0.f;

  const int srow = w * 8 + (lane >> 3), schunk = lane & 7;

#pragma unroll
  for (int p = 0; p < 2; ++p) {
    const int rr = srow + 32 * p;
    const int cc = (schunk ^ (rr & 7)) << 3;
    gload16(kbase + (size_t)rr * kld + cc, (char*)Ks + p * 4096 + w * 1024);
    gload16(vbase + (size_t)rr * 2048 + cc, (char*)Vs + p * 4096 + w * 1024);
  }
  asm volatile("s_waitcnt vmcnt(0)" ::: "memory");
  __syncthreads();

  for (int it = 0; it < 32; ++it) {
    const int cur = it & 1;
    if (it < 31) {
      const int s1 = (it + 1) * 64;
#pragma unroll
      for (int p = 0; p < 2; ++p) {
        const int rr = srow + 32 * p;
        const int cc = (schunk ^ (rr & 7)) << 3;
        gload16(kbase + (size_t)(s1 + rr) * kld + cc,
                (char*)Ks + (cur ^ 1) * 8192 + p * 4096 + w * 1024);
        gload16(vbase + (size_t)rr * 2048 + s1 + cc,
                (char*)Vs + (cur ^ 1) * 8192 + p * 4096 + w * 1024);
      }
    }
    const int s0 = it * 64;
    const short* Kc = Ks[cur];
    const short* Vc = Vs[cur];

    f32x4 sa[4];
#pragma unroll
    for (int st = 0; st < 4; ++st) {
      bf16x8 kf0 = *reinterpret_cast<const bf16x8*>(&Kc[swz(st * 16 + r, g * 8)]);
      bf16x8 kf1 = *reinterpret_cast<const bf16x8*>(&Kc[swz(st * 16 + r, 32 + g * 8)]);
      f32x4 z = {0.f, 0.f, 0.f, 0.f};
      z = mfma16(kf0, qf0, z);
      z = mfma16(kf1, qf1, z);
      sa[st] = z;
    }
    float sv[16];
    float pmax = -INFINITY;
#pragma unroll
    for (int st = 0; st < 4; ++st) {
      const float4 mv = *reinterpret_cast<const float4*>(mask + s0 + st * 16 + 4 * g);
#pragma unroll
      for (int j = 0; j < 4; ++j) {
        float xx = sa[st][j] + ((const float*)&mv)[j];
        sv[st * 4 + j] = xx;
        pmax = fmaxf(pmax, xx);
      }
    }
    pmax = fmaxf(pmax, __shfl_xor(pmax, 16));
    pmax = fmaxf(pmax, __shfl_xor(pmax, 32));
    float m_new = fmaxf(m_run, pmax);
    float corr = __expf(m_run - m_new);
    float psum = 0.f;
    short pb[16];
#pragma unroll
    for (int i = 0; i < 16; ++i) {
      float p = __expf(sv[i] - m_new);
      psum += p;
      pb[i] = f2bf(p);
    }
    psum += __shfl_xor(psum, 16);
    psum += __shfl_xor(psum, 32);
    l_run = l_run * corr + psum;
    m_run = m_new;
#pragma unroll
    for (int dt = 0; dt < 4; ++dt)
#pragma unroll
      for (int j = 0; j < 4; ++j) oacc[dt][j] *= corr;

#pragma unroll
    for (int hs = 0; hs < 2; ++hs) {
      bf16x8 pf = { pb[hs * 8 + 0], pb[hs * 8 + 1], pb[hs * 8 + 2], pb[hs * 8 + 3],
                    pb[hs * 8 + 4], pb[hs * 8 + 5], pb[hs * 8 + 6], pb[hs * 8 + 7] };
#pragma unroll
      for (int dt = 0; dt < 4; ++dt) {
        int d = dt * 16 + r;
        int c1 = 4 * g + 32 * hs;
        bf16x4 va  = *reinterpret_cast<const bf16x4*>(&Vc[swz(d, c1)]);
        bf16x4 vb2 = *reinterpret_cast<const bf16x4*>(&Vc[swz(d, c1 + 16)]);
        bf16x8 vf = { va[0], va[1], va[2], va[3], vb2[0], vb2[1], vb2[2], vb2[3] };
        oacc[dt] = mfma16(vf, pf, oacc[dt]);
      }
    }
    asm volatile("s_waitcnt vmcnt(0)" ::: "memory");
    __syncthreads();
  }
  float inv = 1.f / l_run;
#pragma unroll
  for (int dt = 0; dt < 4; ++dt) {
    bf16x4 ov = { f2bf(oacc[dt][0] * inv), f2bf(oacc[dt][1] * inv),
                  f2bf(oacc[dt][2] * inv), f2bf(oacc[dt][3] * inv) };
    *reinterpret_cast<bf16x4*>(o + (size_t)qrow * 1024 + h * 64 + dt * 16 + 4 * g) = ov;
  }
}

// ---------- launch ----------
extern "C" void kernel_launch(void* const* d_in, const int* in_sizes, int n_in,
                              void* d_out, int out_size, void* d_ws, size_t ws_size,
                              hipStream_t stream) {
  const int*   ids   = (const int*)d_in[0];
  const float* mask  = (const float*)d_in[1];
  const float* tok   = (const float*)d_in[2];
  const float* pos   = (const float*)d_in[3];
  const float* qW    = (const float*)d_in[4];
  const float* qbias = (const float*)d_in[5];
  const float* kW    = (const float*)d_in[6];
  const float* kbias = (const float*)d_in[7];
  const float* vW    = (const float*)d_in[8];
  const float* vbias = (const float*)d_in[9];
  const float* oW    = (const float*)d_in[10];
  const float* obias = (const float*)d_in[11];
  const float* m1W   = (const float*)d_in[12];
  const float* m1b   = (const float*)d_in[13];
  const float* m2W   = (const float*)d_in[14];
  const float* m2b   = (const float*)d_in[15];
  const float* ln1g  = (const float*)d_in[16];
  const float* ln1b  = (const float*)d_in[17];
  const float* ln2g  = (const float*)d_in[18];
  const float* ln2b  = (const float*)d_in[19];
  const float* lnfg  = (const float*)d_in[20];
  const float* lnfb  = (const float*)d_in[21];
  const float* headW = (const float*)d_in[22];
  float* out = (float*)d_out;

  char* ws = (char*)d_ws;
  float* x   = (float*)ws;                        // 8 MB
  short* xb  = (short*)(ws + 8388608ull);         // 4 MB

  const size_t OFF_QKV  = 12582912ull;   // 6 MB  bf16 [2048][1536]
  const size_t OFF_AO   = 18874368ull;   // 4 MB
  const size_t OFF_FF   = 23068672ull;   // 16 MB (first 1 MB aliased as vt between QKV-GEMM and attn)
  const size_t OFF_BQ   = 39845888ull;   // 24 KB f32 [4][1536]
  const size_t OFF_WQKV = 39870464ull;   // 12 MB bf16 [4][1536][1024]
  const size_t OFF_WO   = 52453376ull;   // 8 MB  bf16 [4][1024][1024]
  const size_t OFF_WM1  = 60841984ull;   // 32 MB bf16 [4][4096][1024]
  const size_t OFF_WM2  = 94396416ull;   // 32 MB bf16 [4][1024][4096]
  const size_t OFF_WH   = 127950848ull;  // 64 MB bf16 [32000][1024]
  const size_t NEED     = 193486848ull;

  if (ws_size >= NEED) {
    short* qkv  = (short*)(ws + OFF_QKV);
    short* ao   = (short*)(ws + OFF_AO);
    short* ff   = (short*)(ws + OFF_FF);
    short* vt   = ff;  // alias: ff dead during QKV->attn window
    float* bqv  = (float*)(ws + OFF_BQ);
    short* Wqkv = (short*)(ws + OFF_WQKV);
    short* Wo   = (short*)(ws + OFF_WO);
    short* Wm1  = (short*)(ws + OFF_WM1);
    short* Wm2  = (short*)(ws + OFF_WM2);
    short* Wh   = (short*)(ws + OFF_WH);

    tcvt_k<<<dim3(16, 8, 4), 256, 0, stream>>>(qW, Wqkv, 1024, 1048576ull, 1572864ull, 0, 1024, 0.125f);
    tcvt_k<<<dim3(4, 8, 4),  256, 0, stream>>>(kW, Wqkv, 256,  262144ull,  1572864ull, 1024, 1024, 1.f);
    tcvt_k<<<dim3(4, 8, 4),  256, 0, stream>>>(vW, Wqkv, 256,  262144ull,  1572864ull, 1280, 1024, 1.f);
    tcvt_k<<<dim3(16, 8, 4), 256, 0, stream>>>(oW, Wo, 1024, 1048576ull, 1048576ull, 0, 1024, 1.f);
    tcvt_k<<<dim3(64, 8, 4), 256, 0, stream>>>(m1W, Wm1, 4096, 4194304ull, 4194304ull, 0, 1024, 1.f);
    tcvt_k<<<dim3(16, 32, 4), 256, 0, stream>>>(m2W, Wm2, 1024, 4194304ull, 4194304ull, 0, 4096, 1.f);
    tcvt_k<<<dim3(500, 8, 1), 256, 0, stream>>>(headW, Wh, 32000, 0ull, 0ull, 0, 1024, 1.f);
    bqkv_k<<<dim3(6, 4), 256, 0, stream>>>(qbias, kbias, vbias, bqv);

    embed_k<<<512, 256, 0, stream>>>(ids, tok, pos, x);

    for (int l = 0; l < 4; ++l) {
      short* Wq_l  = Wqkv + (size_t)l * 1536 * 1024;
      short* Wo_l  = Wo   + (size_t)l * 1024 * 1024;
      short* Wm1_l = Wm1  + (size_t)l * 4096 * 1024;
      short* Wm2_l = Wm2  + (size_t)l * 1024 * 4096;

      ln_k<<<512, 256, 0, stream>>>(x, ln1g + l * 1024, ln1b + l * 1024, xb);
      gemm_bt<4, 0, 1><<<dim3(24, 16), 256, 0, stream>>>(xb, Wq_l, bqv + l * 1536, nullptr,
                                                         qkv, 2048, 1536, 1024, 0, vt);
      attn_k<<<dim3(32, 16), 256, 0, stream>>>(qkv, 1536, qkv + 1024, 1536, vt, mask, ao);
      gemm_bt<2, 0, 1><<<dim3(16, 16), 256, 0, stream>>>(ao, Wo_l, obias + l * 1024, x,
                                                         x, 2048, 1024, 1024, 0, nullptr);
      ln_k<<<512, 256, 0, stream>>>(x, ln2g + l * 1024, ln2b + l * 1024, xb);
      gemm_bt<1, 1, 1><<<dim3(64, 16), 256, 0, stream>>>(xb, Wm1_l, m1b + l * 4096, nullptr,
                                                         ff, 2048, 4096, 1024, 0, nullptr);
      gemm_bt<2, 1, 1><<<dim3(16, 16), 256, 0, stream>>>(ff, Wm2_l, m2b + l * 1024, x,
                                                         x, 2048, 1024, 4096, 0, nullptr);
    }
    ln_k<<<512, 256, 0, stream>>>(x, lnfg, lnfb, xb);
    gemm_bt<3, 1, 0><<<dim3(250, 16), 256, 0, stream>>>(xb, Wh, nullptr, nullptr,
                                                        out, 2048, 32000, 1024, 0, nullptr);
  } else {
    // fallback: f32-weight GEMMs, needs < 40 MB ws
    short* qbf = (short*)(ws + (12u << 20));
    short* kbf = (short*)(ws + (16u << 20));
    short* vbf = (short*)(ws + (17u << 20));
    short* ao  = (short*)(ws + (18u << 20));
    short* ff  = (short*)(ws + (22u << 20));
    short* vtf = (short*)(ws + (38u << 20));

    embed_k<<<512, 256, 0, stream>>>(ids, tok, pos, x);
    for (int l = 0; l < 4; ++l) {
      ln_k<<<512, 256, 0, stream>>>(x, ln1g + l * 1024, ln1b + l * 1024, xb);
      gemm_k<0><<<dim3(8, 16), 256, 0, stream>>>(xb, qW + (size_t)l * 1024 * 1024,
          qbias + l * 1024, nullptr, qbf, 2048, 1024, 1024, 0.125f);
      gemm_k<0><<<dim3(2, 16), 256, 0, stream>>>(xb, kW + (size_t)l * 1024 * 256,
          kbias + l * 256, nullptr, kbf, 2048, 256, 1024, 1.f);
      gemm_k<0><<<dim3(2, 16), 256, 0, stream>>>(xb, vW + (size_t)l * 1024 * 256,
          vbias + l * 256, nullptr, vbf, 2048, 256, 1024, 1.f);
      vtr_k<<<dim3(32, 4), 256, 0, stream>>>(vbf, 256, vtf);
      attn_k<<<dim3(32, 16), 256, 0, stream>>>(qbf, 1024, kbf, 256, vtf, mask, ao);
      gemm_k<2><<<dim3(8, 16), 256, 0, stream>>>(ao, oW + (size_t)l * 1024 * 1024,
          obias + l * 1024, x, x, 2048, 1024, 1024, 1.f);
      ln_k<<<512, 256, 0, stream>>>(x, ln2g + l * 1024, ln2b + l * 1024, xb);
      gemm_k<1><<<dim3(32, 16), 256, 0, stream>>>(xb, m1W + (size_t)l * 1024 * 4096,
          m1b + l * 4096, nullptr, ff, 2048, 4096, 1024, 1.f);
      gemm_k<2><<<dim3(8, 16), 256, 0, stream>>>(ff, m2W + (size_t)l * 4096 * 1024,
          m2b + l * 1024, x, x, 2048, 1024, 4096, 1.f);
    }
    ln_k<<<512, 256, 0, stream>>>(x, lnfg, lnfb, xb);
    gemm_k<3><<<dim3(250, 16), 256, 0, stream>>>(xb, headW, nullptr, nullptr, out,
        2048, 32000, 1024, 1.f);
  }
}

// Round 9
// 988.225 us; speedup vs baseline: 1.2652x; 1.1803x over previous
//
#include <hip/hip_runtime.h>
#include <stdint.h>
#include <math.h>

// ---------- types ----------
typedef __attribute__((ext_vector_type(8))) short bf16x8;   // 8 bf16 (4 VGPR)
typedef __attribute__((ext_vector_type(4))) short bf16x4;
typedef __attribute__((ext_vector_type(4))) float f32x4;

__device__ __forceinline__ short f2bf(float f) {
  unsigned u = __builtin_bit_cast(unsigned, f);
  unsigned r = u + 0x7fffu + ((u >> 16) & 1u);
  return (short)(r >> 16);
}

__device__ __forceinline__ f32x4 mfma16(bf16x8 a, bf16x8 b, f32x4 c) {
  return __builtin_amdgcn_mfma_f32_16x16x32_bf16(a, b, c, 0, 0, 0);
}

// async global->LDS, 16B per lane. LDS dest = wave-uniform base + lane*16.
__device__ __forceinline__ void gload16(const void* g, void* l) {
  __builtin_amdgcn_global_load_lds((const __attribute__((address_space(1))) void*)g,
                                   (__attribute__((address_space(3))) void*)l, 16, 0, 0);
}

// LDS tile index: row-major [rows][64] bf16, 16B-chunk XOR swizzle on row&7.
__device__ __forceinline__ int swz(int row, int col) {
  return row * 64 + (((col >> 3) ^ (row & 7)) << 3) + (col & 7);
}

// ---------- embedding (4 rows/block, wave per row) ----------
__global__ __launch_bounds__(256) void embed_k(const int* __restrict__ ids,
                                               const float* __restrict__ tok,
                                               const float* __restrict__ pos,
                                               float* __restrict__ x) {
  const int t = threadIdx.x, w = t >> 6, lane = t & 63;
  const int row = blockIdx.x * 4 + w;
  const int id = ids[row];
#pragma unroll
  for (int i = 0; i < 4; ++i) {
    const int c = (i * 64 + lane) * 4;
    const float4 a = *reinterpret_cast<const float4*>(tok + (size_t)id * 1024 + c);
    const float4 b = *reinterpret_cast<const float4*>(pos + (size_t)row * 1024 + c);
    float4 o = make_float4(a.x + b.x, a.y + b.y, a.z + b.z, a.w + b.w);
    *reinterpret_cast<float4*>(x + (size_t)row * 1024 + c) = o;
  }
}

// ---------- layernorm (wave per row, 4 rows/block, no LDS/barrier) ----------
__global__ __launch_bounds__(256) void ln_k(const float* __restrict__ x,
                                            const float* __restrict__ gw,
                                            const float* __restrict__ bw,
                                            short* __restrict__ out) {
  const int t = threadIdx.x, w = t >> 6, lane = t & 63;
  const int row = blockIdx.x * 4 + w;
  float4 v[4];
  float s = 0.f, q = 0.f;
#pragma unroll
  for (int i = 0; i < 4; ++i) {
    v[i] = *reinterpret_cast<const float4*>(x + (size_t)row * 1024 + (i * 64 + lane) * 4);
    s += v[i].x + v[i].y + v[i].z + v[i].w;
    q += v[i].x * v[i].x + v[i].y * v[i].y + v[i].z * v[i].z + v[i].w * v[i].w;
  }
#pragma unroll
  for (int o = 32; o > 0; o >>= 1) { s += __shfl_xor(s, o); q += __shfl_xor(q, o); }
  const float mean = s * (1.f / 1024.f);
  const float var  = q * (1.f / 1024.f) - mean * mean;
  const float rstd = rsqrtf(var + 1e-5f);
#pragma unroll
  for (int i = 0; i < 4; ++i) {
    const int c = (i * 64 + lane) * 4;
    const float4 gv = *reinterpret_cast<const float4*>(gw + c);
    const float4 bv = *reinterpret_cast<const float4*>(bw + c);
    bf16x4 ov = { f2bf((v[i].x - mean) * rstd * gv.x + bv.x),
                  f2bf((v[i].y - mean) * rstd * gv.y + bv.y),
                  f2bf((v[i].z - mean) * rstd * gv.z + bv.z),
                  f2bf((v[i].w - mean) * rstd * gv.w + bv.w) };
    *reinterpret_cast<bf16x4*>(out + (size_t)row * 1024 + c) = ov;
  }
}

// ---------- merged weight transpose+convert: one launch for all 7 weights ----------
struct TSeg {
  const float* src; short* dst;
  unsigned long long inStride, outStride;
  int N, nbx, nbxy, rowOff, ldOut, blkEnd;
  float scale;
};
struct TTab { TSeg s[7]; };

__global__ __launch_bounds__(256) void tcvt_all(TTab tab) {
  const int b = blockIdx.x;
  int si = 0;
  while (b >= tab.s[si].blkEnd) ++si;
  const TSeg sg = tab.s[si];
  const int base = (si == 0) ? 0 : tab.s[si - 1].blkEnd;
  int lb = b - base;
  const int z = lb / sg.nbxy; lb -= z * sg.nbxy;
  const int by = lb / sg.nbx;
  const int bx = lb - by * sg.nbx;

  __shared__ float T[128][68];
  const float* Win = sg.src + (size_t)z * sg.inStride;
  short* Wout = sg.dst + (size_t)z * sg.outStride;
  const int n0 = bx * 64, k0 = by * 128;
  const int t = threadIdx.x;
  const int nc = (t & 15) * 4, kr = t >> 4;
#pragma unroll
  for (int p = 0; p < 8; ++p) {
    const float4 v = *reinterpret_cast<const float4*>(Win + (size_t)(k0 + kr + 16 * p) * sg.N + n0 + nc);
    T[kr + 16 * p][nc + 0] = v.x;
    T[kr + 16 * p][nc + 1] = v.y;
    T[kr + 16 * p][nc + 2] = v.z;
    T[kr + 16 * p][nc + 3] = v.w;
  }
  __syncthreads();
  const int n = t >> 2, ks = (t & 3) * 32;
  short tmp[32];
#pragma unroll
  for (int i = 0; i < 32; ++i) tmp[i] = f2bf(T[ks + i][n] * sg.scale);
  short* op = Wout + (size_t)(sg.rowOff + n0 + n) * sg.ldOut + k0 + ks;
#pragma unroll
  for (int c = 0; c < 4; ++c)
    *reinterpret_cast<bf16x8*>(op + c * 8) = *reinterpret_cast<bf16x8*>(tmp + c * 8);
}

// concat qkv bias (q scaled by 0.125)
__global__ __launch_bounds__(256) void bqkv_k(const float* __restrict__ qb,
                                              const float* __restrict__ kb,
                                              const float* __restrict__ vb,
                                              float* __restrict__ o) {
  int l = blockIdx.y;
  int c = blockIdx.x * 256 + threadIdx.x;
  float v;
  if (c < 1024) v = qb[l * 1024 + c] * 0.125f;
  else if (c < 1280) v = kb[l * 256 + c - 1024];
  else v = vb[l * 256 + c - 1280];
  o[l * 1536 + c] = v;
}

// ---------- split-K combine: x += t0 + t1 + bias  (2048x1024 f32) ----------
__global__ __launch_bounds__(256) void comb_k(const float* __restrict__ t0,
                                              const float* __restrict__ t1,
                                              const float* __restrict__ bias,
                                              float* __restrict__ x) {
  const int t = threadIdx.x, w = t >> 6, lane = t & 63;
  const int row = blockIdx.x * 4 + w;
#pragma unroll
  for (int i = 0; i < 4; ++i) {
    const int c = (i * 64 + lane) * 4;
    const size_t o = (size_t)row * 1024 + c;
    const float4 a = *reinterpret_cast<const float4*>(t0 + o);
    const float4 b = *reinterpret_cast<const float4*>(t1 + o);
    const float4 bb = *reinterpret_cast<const float4*>(bias + c);
    const float4 xx = *reinterpret_cast<const float4*>(x + o);
    float4 r = make_float4(xx.x + a.x + b.x + bb.x, xx.y + a.y + b.y + bb.y,
                           xx.z + a.z + b.z + bb.z, xx.w + a.w + b.w + bb.w);
    *reinterpret_cast<float4*>(x + o) = r;
  }
}

// ---------- V transpose (fallback path only) ----------
__global__ __launch_bounds__(256) void vtr_k(const short* __restrict__ v, int vld,
                                             short* __restrict__ vt) {
  __shared__ short T[64][80];
  const int kvh = blockIdx.y;
  const int s0 = blockIdx.x * 64;
  const int t = threadIdx.x;
  const int row = t >> 3, ch = t & 7;
#pragma unroll
  for (int p = 0; p < 2; ++p) {
    int s = row + 32 * p;
    bf16x8 vv = *reinterpret_cast<const bf16x8*>(v + (size_t)(s0 + s) * vld + kvh * 64 + ch * 8);
    *reinterpret_cast<bf16x8*>(&T[s][ch * 8]) = vv;
  }
  __syncthreads();
#pragma unroll
  for (int p = 0; p < 2; ++p) {
    int d = row + 32 * p;
    short tmp[8];
#pragma unroll
    for (int i = 0; i < 8; ++i) tmp[i] = T[ch * 8 + i][d];
    *reinterpret_cast<bf16x8*>(vt + (size_t)(kvh * 64 + d) * 2048 + s0 + ch * 8) =
        *reinterpret_cast<bf16x8*>(tmp);
  }
}

// ---------- GEMM (m97 structure): C[M,N] = A_bf16[M,K] @ Wt_bf16[N,K]^T ----------
// EPI: 0 bf16 out (acc+bias); 1 bf16 GELU(acc+bias); 2 f32 resid+acc+bias;
//      3 f32 acc (z-slice partial: out + z*M*N); 4 = EPI0 + V^T store to vt
// XSWZ: 0 identity; 1 m-fastest bijective XCD chunking
// TILE: 0 = 128x128; 1 = 128x64
// K is the row stride; [kBeg,kEnd) is the K-range; blockIdx.z shifts the range
// by z*(kEnd-kBeg) (concurrent split-K; EPI3 writes partial at z*M*N).
template <int EPI, int XSWZ, int TILE>
__global__ __launch_bounds__(256, 4)
void gemm_bt(const short* __restrict__ A, const short* __restrict__ Wt,
             const float* __restrict__ bias, const float* __restrict__ resid,
             void* __restrict__ out, int M, int N, int K, int kBeg, int kEnd,
             int nbOff, short* __restrict__ vt) {
  constexpr int BN   = (TILE == 0) ? 128 : 64;
  constexpr int WN   = (TILE == 0) ? 64 : 32;
  constexpr int NT   = (TILE == 0) ? 4 : 2;
  constexpr int BISS = (TILE == 0) ? 4 : 2;
  __shared__ short As[128 * 64];
  __shared__ short Bs[BN * 64];
  const int t = threadIdx.x;
  const int lane = t & 63, w = t >> 6;
  const int g = lane >> 4, r = lane & 15;
  const int wr = w >> 1, wc = w & 1;

  int bx = blockIdx.x, by = blockIdx.y;
  if (XSWZ == 1) {
    const int nbx = gridDim.x, nby = gridDim.y, nwg = nbx * nby;
    const int bid = by * nbx + bx;
    const int q = nwg >> 3, rr = nwg & 7;
    const int xcd = bid & 7, loc = bid >> 3;
    const int sw = (xcd < rr ? xcd * (q + 1) : rr * (q + 1) + (xcd - rr) * q) + loc;
    by = sw % nby; bx = sw / nby;
  }
  const int m0 = by * 128, n0 = (bx + nbOff) * BN;
  const int kShift = (int)blockIdx.z * (kEnd - kBeg);
  const size_t zOfs = (size_t)blockIdx.z * (size_t)M * (size_t)N;

  f32x4 acc[4][NT];
#pragma unroll
  for (int i = 0; i < 4; ++i)
#pragma unroll
    for (int j = 0; j < NT; ++j) { f32x4 z = {0.f, 0.f, 0.f, 0.f}; acc[i][j] = z; }

  const int srow = lane >> 3, sslot = lane & 7;

  for (int k0 = kBeg + kShift; k0 < kEnd + kShift; k0 += 64) {
#pragma unroll
    for (int i = 0; i < 4; ++i) {
      const int rowA = w * 32 + i * 8 + srow;
      const int colA = (sslot ^ (srow & 7)) << 3;
      gload16(A + (size_t)(m0 + rowA) * K + k0 + colA, &As[(w * 32 + i * 8) * 64]);
    }
#pragma unroll
    for (int i = 0; i < BISS; ++i) {
      const int rowB = w * (8 * BISS) + i * 8 + srow;
      const int colB = (sslot ^ (srow & 7)) << 3;
      gload16(Wt + (size_t)(n0 + rowB) * K + k0 + colB, &Bs[(w * (8 * BISS) + i * 8) * 64]);
    }
    __syncthreads();
#pragma unroll
    for (int kk = 0; kk < 64; kk += 32) {
      bf16x8 af[4], bfg[NT];
#pragma unroll
      for (int mt = 0; mt < 4; ++mt)
        af[mt] = *reinterpret_cast<const bf16x8*>(&As[swz(wr * 64 + mt * 16 + r, kk + g * 8)]);
#pragma unroll
      for (int nt = 0; nt < NT; ++nt)
        bfg[nt] = *reinterpret_cast<const bf16x8*>(&Bs[swz(wc * WN + nt * 16 + r, kk + g * 8)]);
#pragma unroll
      for (int mt = 0; mt < 4; ++mt)
#pragma unroll
        for (int nt = 0; nt < NT; ++nt)
          acc[mt][nt] = mfma16(af[mt], bfg[nt], acc[mt][nt]);
    }
    __syncthreads();
  }
#pragma unroll
  for (int nt = 0; nt < NT; ++nt) {
    const int col = n0 + wc * WN + nt * 16 + r;
    const float bv = (EPI == 3) ? 0.f : bias[col];
#pragma unroll
    for (int mt = 0; mt < 4; ++mt) {
      const int rowb = m0 + wr * 64 + mt * 16 + 4 * g;
      short vs[4];
#pragma unroll
      for (int j = 0; j < 4; ++j) {
        const int row = rowb + j;
        const size_t oi = (size_t)row * N + col;
        float vv = acc[mt][nt][j] + bv;
        if (EPI == 0) {
          ((short*)out)[oi] = f2bf(vv);
        } else if (EPI == 1) {
          vv = 0.5f * vv * (1.f + erff(vv * 0.70710678118654752f));
          ((short*)out)[oi] = f2bf(vv);
        } else if (EPI == 2) {
          ((float*)out)[oi] = resid[oi] + vv;
        } else if (EPI == 3) {
          ((float*)out)[oi + zOfs] = vv;
        } else {  // EPI 4
          short bb = f2bf(vv);
          ((short*)out)[oi] = bb;
          vs[j] = bb;
        }
      }
      if (EPI == 4 && col >= 1280) {
        bf16x4 pk = { vs[0], vs[1], vs[2], vs[3] };
        *reinterpret_cast<bf16x4*>(vt + (size_t)(col - 1280) * 2048 + rowb) = pk;
      }
    }
  }
}

// ---------- legacy GEMM (f32 weights) — fallback if ws too small ----------
template <int EPI>
__global__ __launch_bounds__(256)
void gemm_k(const short* __restrict__ A, const float* __restrict__ W,
            const float* __restrict__ bias, const float* resid, void* out,
            int M, int N, int K, float scale) {
  __shared__ short As[128 * 64];
  __shared__ short Bs[128 * 64];
  const int t = threadIdx.x;
  const int lane = t & 63;
  const int g = lane >> 4, r = lane & 15;
  const int wid = t >> 6, wr = wid >> 1, wc = wid & 1;
  const int m0 = blockIdx.y * 128, n0 = blockIdx.x * 128;
  f32x4 acc[4][4];
#pragma unroll
  for (int i = 0; i < 4; ++i)
#pragma unroll
    for (int j = 0; j < 4; ++j) { f32x4 z = {0.f, 0.f, 0.f, 0.f}; acc[i][j] = z; }
  const int arow = t >> 3, ac = t & 7;
  const int bnn = t >> 1, bkh = t & 1;
  for (int k0 = 0; k0 < K; k0 += 64) {
#pragma unroll
    for (int p = 0; p < 4; ++p) {
      int row = arow + 32 * p;
      bf16x8 av = *reinterpret_cast<const bf16x8*>(A + (size_t)(m0 + row) * K + k0 + ac * 8);
      *reinterpret_cast<bf16x8*>(&As[swz(row, ac * 8)]) = av;
    }
#pragma unroll
    for (int p = 0; p < 8; ++p) {
      int kg = 4 * (bkh + 2 * p);
      const float* wp = W + (size_t)(k0 + kg) * N + n0 + bnn;
      bf16x4 wv = { f2bf(wp[0]), f2bf(wp[(size_t)N]), f2bf(wp[(size_t)2 * N]), f2bf(wp[(size_t)3 * N]) };
      *reinterpret_cast<bf16x4*>(&Bs[swz(bnn, kg)]) = wv;
    }
    __syncthreads();
#pragma unroll
    for (int kk = 0; kk < 64; kk += 32) {
      bf16x8 af[4], bfg[4];
#pragma unroll
      for (int mt = 0; mt < 4; ++mt)
        af[mt] = *reinterpret_cast<const bf16x8*>(&As[swz(wr * 64 + mt * 16 + r, kk + g * 8)]);
#pragma unroll
      for (int nt = 0; nt < 4; ++nt)
        bfg[nt] = *reinterpret_cast<const bf16x8*>(&Bs[swz(wc * 64 + nt * 16 + r, kk + g * 8)]);
#pragma unroll
      for (int mt = 0; mt < 4; ++mt)
#pragma unroll
        for (int nt = 0; nt < 4; ++nt)
          acc[mt][nt] = mfma16(af[mt], bfg[nt], acc[mt][nt]);
    }
    __syncthreads();
  }
#pragma unroll
  for (int nt = 0; nt < 4; ++nt) {
    const int col = n0 + wc * 64 + nt * 16 + r;
    const float bv = (EPI == 3) ? 0.f : bias[col];
#pragma unroll
    for (int mt = 0; mt < 4; ++mt) {
#pragma unroll
      for (int j = 0; j < 4; ++j) {
        const int row = m0 + wr * 64 + mt * 16 + 4 * g + j;
        const size_t oi = (size_t)row * N + col;
        float vv = acc[mt][nt][j] + bv;
        if (EPI == 0) {
          ((short*)out)[oi] = f2bf(vv * scale);
        } else if (EPI == 1) {
          vv = 0.5f * vv * (1.f + erff(vv * 0.70710678118654752f));
          ((short*)out)[oi] = f2bf(vv);
        } else if (EPI == 2) {
          ((float*)out)[oi] = resid[oi] + vv;
        } else {
          ((float*)out)[oi] = vv;
        }
      }
    }
  }
}

// ---------- flash-style GQA attention (dbuf, gload_lds staging) ----------
__global__ __launch_bounds__(256) void attn_k(const short* __restrict__ q, int qld,
                                              const short* __restrict__ k, int kld,
                                              const short* __restrict__ vt,
                                              const float* __restrict__ mask,
                                              short* __restrict__ o) {
  __shared__ short Ks[2][64 * 64];  // [s][d], 16B-chunk swizzled
  __shared__ short Vs[2][64 * 64];  // [d][s], 16B-chunk swizzled
  const int t = threadIdx.x, lane = t & 63, w = t >> 6;
  const int g = lane >> 4, r = lane & 15;
  const int h = blockIdx.y, qb = blockIdx.x, kvh = h >> 2;
  const int qrow = qb * 64 + w * 16 + r;

  const short* qp = q + (size_t)qrow * qld + h * 64;
  bf16x8 qf0 = *reinterpret_cast<const bf16x8*>(qp + g * 8);
  bf16x8 qf1 = *reinterpret_cast<const bf16x8*>(qp + 32 + g * 8);

  const short* kbase = k + kvh * 64;                   // + s*kld
  const short* vbase = vt + (size_t)kvh * 64 * 2048;   // + d*2048 + s

  f32x4 oacc[4];
#pragma unroll
  for (int i = 0; i < 4; ++i) { f32x4 z = {0.f, 0.f, 0.f, 0.f}; oacc[i] = z; }
  float m_run = -INFINITY, l_run = 0.f;

  const int srow = w * 8 + (lane >> 3), schunk = lane & 7;

#pragma unroll
  for (int p = 0; p < 2; ++p) {
    const int rr = srow + 32 * p;
    const int cc = (schunk ^ (rr & 7)) << 3;
    gload16(kbase + (size_t)rr * kld + cc, (char*)Ks + p * 4096 + w * 1024);
    gload16(vbase + (size_t)rr * 2048 + cc, (char*)Vs + p * 4096 + w * 1024);
  }
  asm volatile("s_waitcnt vmcnt(0)" ::: "memory");
  __syncthreads();

  for (int it = 0; it < 32; ++it) {
    const int cur = it & 1;
    if (it < 31) {
      const int s1 = (it + 1) * 64;
#pragma unroll
      for (int p = 0; p < 2; ++p) {
        const int rr = srow + 32 * p;
        const int cc = (schunk ^ (rr & 7)) << 3;
        gload16(kbase + (size_t)(s1 + rr) * kld + cc,
                (char*)Ks + (cur ^ 1) * 8192 + p * 4096 + w * 1024);
        gload16(vbase + (size_t)rr * 2048 + s1 + cc,
                (char*)Vs + (cur ^ 1) * 8192 + p * 4096 + w * 1024);
      }
    }
    const int s0 = it * 64;
    const short* Kc = Ks[cur];
    const short* Vc = Vs[cur];

    f32x4 sa[4];
#pragma unroll
    for (int st = 0; st < 4; ++st) {
      bf16x8 kf0 = *reinterpret_cast<const bf16x8*>(&Kc[swz(st * 16 + r, g * 8)]);
      bf16x8 kf1 = *reinterpret_cast<const bf16x8*>(&Kc[swz(st * 16 + r, 32 + g * 8)]);
      f32x4 z = {0.f, 0.f, 0.f, 0.f};
      z = mfma16(kf0, qf0, z);
      z = mfma16(kf1, qf1, z);
      sa[st] = z;
    }
    float sv[16];
    float pmax = -INFINITY;
#pragma unroll
    for (int st = 0; st < 4; ++st) {
      const float4 mv = *reinterpret_cast<const float4*>(mask + s0 + st * 16 + 4 * g);
#pragma unroll
      for (int j = 0; j < 4; ++j) {
        float xx = sa[st][j] + ((const float*)&mv)[j];
        sv[st * 4 + j] = xx;
        pmax = fmaxf(pmax, xx);
      }
    }
    pmax = fmaxf(pmax, __shfl_xor(pmax, 16));
    pmax = fmaxf(pmax, __shfl_xor(pmax, 32));
    float m_new = fmaxf(m_run, pmax);
    float corr = __expf(m_run - m_new);
    float psum = 0.f;
    short pb[16];
#pragma unroll
    for (int i = 0; i < 16; ++i) {
      float p = __expf(sv[i] - m_new);
      psum += p;
      pb[i] = f2bf(p);
    }
    psum += __shfl_xor(psum, 16);
    psum += __shfl_xor(psum, 32);
    l_run = l_run * corr + psum;
    m_run = m_new;
#pragma unroll
    for (int dt = 0; dt < 4; ++dt)
#pragma unroll
      for (int j = 0; j < 4; ++j) oacc[dt][j] *= corr;

#pragma unroll
    for (int hs = 0; hs < 2; ++hs) {
      bf16x8 pf = { pb[hs * 8 + 0], pb[hs * 8 + 1], pb[hs * 8 + 2], pb[hs * 8 + 3],
                    pb[hs * 8 + 4], pb[hs * 8 + 5], pb[hs * 8 + 6], pb[hs * 8 + 7] };
#pragma unroll
      for (int dt = 0; dt < 4; ++dt) {
        int d = dt * 16 + r;
        int c1 = 4 * g + 32 * hs;
        bf16x4 va  = *reinterpret_cast<const bf16x4*>(&Vc[swz(d, c1)]);
        bf16x4 vb2 = *reinterpret_cast<const bf16x4*>(&Vc[swz(d, c1 + 16)]);
        bf16x8 vf = { va[0], va[1], va[2], va[3], vb2[0], vb2[1], vb2[2], vb2[3] };
        oacc[dt] = mfma16(vf, pf, oacc[dt]);
      }
    }
    asm volatile("s_waitcnt vmcnt(0)" ::: "memory");
    __syncthreads();
  }
  float inv = 1.f / l_run;
#pragma unroll
  for (int dt = 0; dt < 4; ++dt) {
    bf16x4 ov = { f2bf(oacc[dt][0] * inv), f2bf(oacc[dt][1] * inv),
                  f2bf(oacc[dt][2] * inv), f2bf(oacc[dt][3] * inv) };
    *reinterpret_cast<bf16x4*>(o + (size_t)qrow * 1024 + h * 64 + dt * 16 + 4 * g) = ov;
  }
}

// ---------- launch ----------
extern "C" void kernel_launch(void* const* d_in, const int* in_sizes, int n_in,
                              void* d_out, int out_size, void* d_ws, size_t ws_size,
                              hipStream_t stream) {
  const int*   ids   = (const int*)d_in[0];
  const float* mask  = (const float*)d_in[1];
  const float* tok   = (const float*)d_in[2];
  const float* pos   = (const float*)d_in[3];
  const float* qW    = (const float*)d_in[4];
  const float* qbias = (const float*)d_in[5];
  const float* kW    = (const float*)d_in[6];
  const float* kbias = (const float*)d_in[7];
  const float* vW    = (const float*)d_in[8];
  const float* vbias = (const float*)d_in[9];
  const float* oW    = (const float*)d_in[10];
  const float* obias = (const float*)d_in[11];
  const float* m1W   = (const float*)d_in[12];
  const float* m1b   = (const float*)d_in[13];
  const float* m2W   = (const float*)d_in[14];
  const float* m2b   = (const float*)d_in[15];
  const float* ln1g  = (const float*)d_in[16];
  const float* ln1b  = (const float*)d_in[17];
  const float* ln2g  = (const float*)d_in[18];
  const float* ln2b  = (const float*)d_in[19];
  const float* lnfg  = (const float*)d_in[20];
  const float* lnfb  = (const float*)d_in[21];
  const float* headW = (const float*)d_in[22];
  float* out = (float*)d_out;

  char* ws = (char*)d_ws;
  float* x   = (float*)ws;                        // 8 MB
  short* xb  = (short*)(ws + 8388608ull);         // 4 MB

  const size_t OFF_QKV  = 12582912ull;   // 6 MB  bf16 [2048][1536]
  const size_t OFF_AO   = 18874368ull;   // 4 MB
  const size_t OFF_FF   = 23068672ull;   // 16 MB (first 1 MB aliased as vt)
  const size_t OFF_BQ   = 39845888ull;   // 24 KB f32 [4][1536]
  const size_t OFF_WQKV = 39870464ull;   // 12 MB bf16 [4][1536][1024]
  const size_t OFF_WO   = 52453376ull;   // 8 MB  bf16 [4][1024][1024]
  const size_t OFF_WM1  = 60841984ull;   // 32 MB bf16 [4][4096][1024]
  const size_t OFF_WM2  = 94396416ull;   // 32 MB bf16 [4][1024][4096]
  const size_t OFF_WH   = 127950848ull;  // 64 MB bf16 [32000][1024]
  const size_t OFF_TMP  = 193486848ull;  // 16 MB f32 [2][2048][1024] split-K partials
  const size_t NEED     = 210264064ull;

  if (ws_size >= NEED) {
    short* qkv  = (short*)(ws + OFF_QKV);
    short* ao   = (short*)(ws + OFF_AO);
    short* ff   = (short*)(ws + OFF_FF);
    short* vt   = ff;  // alias: ff dead during QKV->attn window
    float* bqv  = (float*)(ws + OFF_BQ);
    short* Wqkv = (short*)(ws + OFF_WQKV);
    short* Wo   = (short*)(ws + OFF_WO);
    short* Wm1  = (short*)(ws + OFF_WM1);
    short* Wm2  = (short*)(ws + OFF_WM2);
    short* Wh   = (short*)(ws + OFF_WH);
    float* tmp0 = (float*)(ws + OFF_TMP);
    float* tmp1 = tmp0 + 2097152;  // 2048*1024

    // ---- merged weight conversion (one launch) ----
    TTab tab;
    int acc = 0;
    auto seg = [&](int i, const float* src, short* dst, size_t inS, size_t outS,
                   int N, int nbx, int nby, int nbz, int rowOff, int ldOut, float scale) {
      acc += nbx * nby * nbz;
      tab.s[i].src = src;      tab.s[i].dst = dst;
      tab.s[i].inStride = inS; tab.s[i].outStride = outS;
      tab.s[i].N = N;          tab.s[i].nbx = nbx;
      tab.s[i].nbxy = nbx * nby;
      tab.s[i].rowOff = rowOff; tab.s[i].ldOut = ldOut;
      tab.s[i].blkEnd = acc;   tab.s[i].scale = scale;
    };
    seg(0, headW, Wh,   0ull,        0ull,        32000, 500, 8, 1, 0,    1024, 1.f);
    seg(1, m1W,   Wm1,  4194304ull,  4194304ull,  4096,  64,  8, 4, 0,    1024, 1.f);
    seg(2, m2W,   Wm2,  4194304ull,  4194304ull,  1024,  16, 32, 4, 0,    4096, 1.f);
    seg(3, qW,    Wqkv, 1048576ull,  1572864ull,  1024,  16,  8, 4, 0,    1024, 0.125f);
    seg(4, oW,    Wo,   1048576ull,  1048576ull,  1024,  16,  8, 4, 0,    1024, 1.f);
    seg(5, kW,    Wqkv, 262144ull,   1572864ull,  256,   4,   8, 4, 1024, 1024, 1.f);
    seg(6, vW,    Wqkv, 262144ull,   1572864ull,  256,   4,   8, 4, 1280, 1024, 1.f);
    tcvt_all<<<acc, 256, 0, stream>>>(tab);
    bqkv_k<<<dim3(6, 4), 256, 0, stream>>>(qbias, kbias, vbias, bqv);

    embed_k<<<512, 256, 0, stream>>>(ids, tok, pos, x);

    for (int l = 0; l < 4; ++l) {
      short* Wq_l  = Wqkv + (size_t)l * 1536 * 1024;
      short* Wo_l  = Wo   + (size_t)l * 1024 * 1024;
      short* Wm1_l = Wm1  + (size_t)l * 4096 * 1024;
      short* Wm2_l = Wm2  + (size_t)l * 1024 * 4096;

      ln_k<<<512, 256, 0, stream>>>(x, ln1g + l * 1024, ln1b + l * 1024, xb);
      gemm_bt<4, 0, 1><<<dim3(24, 16), 256, 0, stream>>>(xb, Wq_l, bqv + l * 1536, nullptr,
                                                         qkv, 2048, 1536, 1024, 0, 1024, 0, vt);
      attn_k<<<dim3(32, 16), 256, 0, stream>>>(qkv, 1536, qkv + 1024, 1536, vt, mask, ao);
      gemm_bt<2, 0, 1><<<dim3(16, 16), 256, 0, stream>>>(ao, Wo_l, obias + l * 1024, x,
                                                         x, 2048, 1024, 1024, 0, 1024, 0, nullptr);
      ln_k<<<512, 256, 0, stream>>>(x, ln2g + l * 1024, ln2b + l * 1024, xb);
      gemm_bt<1, 1, 1><<<dim3(64, 16), 256, 0, stream>>>(xb, Wm1_l, m1b + l * 4096, nullptr,
                                                         ff, 2048, 4096, 1024, 0, 1024, 0, nullptr);
      // m2: concurrent split-K x2 (z=0 -> tmp0, z=1 -> tmp1), then combine.
      gemm_bt<3, 1, 1><<<dim3(16, 16, 2), 256, 0, stream>>>(ff, Wm2_l, nullptr, nullptr,
                                                            tmp0, 2048, 1024, 4096, 0, 2048, 0, nullptr);
      comb_k<<<512, 256, 0, stream>>>(tmp0, tmp1, m2b + l * 1024, x);
    }
    ln_k<<<512, 256, 0, stream>>>(x, lnfg, lnfb, xb);
    gemm_bt<3, 1, 0><<<dim3(250, 16), 256, 0, stream>>>(xb, Wh, nullptr, nullptr,
                                                        out, 2048, 32000, 1024, 0, 1024, 0, nullptr);
  } else {
    // fallback: f32-weight GEMMs, needs < 40 MB ws
    short* qbf = (short*)(ws + (12u << 20));
    short* kbf = (short*)(ws + (16u << 20));
    short* vbf = (short*)(ws + (17u << 20));
    short* ao  = (short*)(ws + (18u << 20));
    short* ff  = (short*)(ws + (22u << 20));
    short* vtf = (short*)(ws + (38u << 20));

    embed_k<<<512, 256, 0, stream>>>(ids, tok, pos, x);
    for (int l = 0; l < 4; ++l) {
      ln_k<<<512, 256, 0, stream>>>(x, ln1g + l * 1024, ln1b + l * 1024, xb);
      gemm_k<0><<<dim3(8, 16), 256, 0, stream>>>(xb, qW + (size_t)l * 1024 * 1024,
          qbias + l * 1024, nullptr, qbf, 2048, 1024, 1024, 0.125f);
      gemm_k<0><<<dim3(2, 16), 256, 0, stream>>>(xb, kW + (size_t)l * 1024 * 256,
          kbias + l * 256, nullptr, kbf, 2048, 256, 1024, 1.f);
      gemm_k<0><<<dim3(2, 16), 256, 0, stream>>>(xb, vW + (size_t)l * 1024 * 256,
          vbias + l * 256, nullptr, vbf, 2048, 256, 1024, 1.f);
      vtr_k<<<dim3(32, 4), 256, 0, stream>>>(vbf, 256, vtf);
      attn_k<<<dim3(32, 16), 256, 0, stream>>>(qbf, 1024, kbf, 256, vtf, mask, ao);
      gemm_k<2><<<dim3(8, 16), 256, 0, stream>>>(ao, oW + (size_t)l * 1024 * 1024,
          obias + l * 1024, x, x, 2048, 1024, 1024, 1.f);
      ln_k<<<512, 256, 0, stream>>>(x, ln2g + l * 1024, ln2b + l * 1024, xb);
      gemm_k<1><<<dim3(32, 16), 256, 0, stream>>>(xb, m1W + (size_t)l * 1024 * 4096,
          m1b + l * 4096, nullptr, ff, 2048, 4096, 1024, 1.f);
      gemm_k<2><<<dim3(8, 16), 256, 0, stream>>>(ff, m2W + (size_t)l * 4096 * 1024,
          m2b + l * 1024, x, x, 2048, 1024, 4096, 1.f);
    }
    ln_k<<<512, 256, 0, stream>>>(x, lnfg, lnfb, xb);
    gemm_k<3><<<dim3(250, 16), 256, 0, stream>>>(xb, headW, nullptr, nullptr, out,
        2048, 32000, 1024, 1.f);
  }
}

// Round 10
// 970.856 us; speedup vs baseline: 1.2878x; 1.0179x over previous
//
#include <hip/hip_runtime.h>
#include <stdint.h>
#include <math.h>

// ---------- types ----------
typedef __attribute__((ext_vector_type(8))) short bf16x8;   // 8 bf16 (4 VGPR)
typedef __attribute__((ext_vector_type(4))) short bf16x4;
typedef __attribute__((ext_vector_type(4))) float f32x4;

__device__ __forceinline__ short f2bf(float f) {
  unsigned u = __builtin_bit_cast(unsigned, f);
  unsigned r = u + 0x7fffu + ((u >> 16) & 1u);
  return (short)(r >> 16);
}

__device__ __forceinline__ f32x4 mfma16(bf16x8 a, bf16x8 b, f32x4 c) {
  return __builtin_amdgcn_mfma_f32_16x16x32_bf16(a, b, c, 0, 0, 0);
}

// async global->LDS, 16B per lane. LDS dest = wave-uniform base + lane*16.
__device__ __forceinline__ void gload16(const void* g, void* l) {
  __builtin_amdgcn_global_load_lds((const __attribute__((address_space(1))) void*)g,
                                   (__attribute__((address_space(3))) void*)l, 16, 0, 0);
}

// LDS tile index: row-major [rows][64] bf16, 16B-chunk XOR swizzle on row&7.
__device__ __forceinline__ int swz(int row, int col) {
  return row * 64 + (((col >> 3) ^ (row & 7)) << 3) + (col & 7);
}

// ---------- embedding (4 rows/block, wave per row) ----------
__global__ __launch_bounds__(256) void embed_k(const int* __restrict__ ids,
                                               const float* __restrict__ tok,
                                               const float* __restrict__ pos,
                                               float* __restrict__ x) {
  const int t = threadIdx.x, w = t >> 6, lane = t & 63;
  const int row = blockIdx.x * 4 + w;
  const int id = ids[row];
#pragma unroll
  for (int i = 0; i < 4; ++i) {
    const int c = (i * 64 + lane) * 4;
    const float4 a = *reinterpret_cast<const float4*>(tok + (size_t)id * 1024 + c);
    const float4 b = *reinterpret_cast<const float4*>(pos + (size_t)row * 1024 + c);
    float4 o = make_float4(a.x + b.x, a.y + b.y, a.z + b.z, a.w + b.w);
    *reinterpret_cast<float4*>(x + (size_t)row * 1024 + c) = o;
  }
}

// ---------- layernorm (wave per row, 4 rows/block) ----------
__global__ __launch_bounds__(256) void ln_k(const float* __restrict__ x,
                                            const float* __restrict__ gw,
                                            const float* __restrict__ bw,
                                            short* __restrict__ out) {
  const int t = threadIdx.x, w = t >> 6, lane = t & 63;
  const int row = blockIdx.x * 4 + w;
  float4 v[4];
  float s = 0.f, q = 0.f;
#pragma unroll
  for (int i = 0; i < 4; ++i) {
    v[i] = *reinterpret_cast<const float4*>(x + (size_t)row * 1024 + (i * 64 + lane) * 4);
    s += v[i].x + v[i].y + v[i].z + v[i].w;
    q += v[i].x * v[i].x + v[i].y * v[i].y + v[i].z * v[i].z + v[i].w * v[i].w;
  }
#pragma unroll
  for (int o = 32; o > 0; o >>= 1) { s += __shfl_xor(s, o); q += __shfl_xor(q, o); }
  const float mean = s * (1.f / 1024.f);
  const float var  = q * (1.f / 1024.f) - mean * mean;
  const float rstd = rsqrtf(var + 1e-5f);
#pragma unroll
  for (int i = 0; i < 4; ++i) {
    const int c = (i * 64 + lane) * 4;
    const float4 gv = *reinterpret_cast<const float4*>(gw + c);
    const float4 bv = *reinterpret_cast<const float4*>(bw + c);
    bf16x4 ov = { f2bf((v[i].x - mean) * rstd * gv.x + bv.x),
                  f2bf((v[i].y - mean) * rstd * gv.y + bv.y),
                  f2bf((v[i].z - mean) * rstd * gv.z + bv.z),
                  f2bf((v[i].w - mean) * rstd * gv.w + bv.w) };
    *reinterpret_cast<bf16x4*>(out + (size_t)row * 1024 + c) = ov;
  }
}

// ---------- fused split-K combine + layernorm ----------
// x += t0 + t1 + bias; then LN(x) -> out (bf16). One pass, no standalone combine.
__global__ __launch_bounds__(256) void comb_ln(const float* __restrict__ t0,
                                               const float* __restrict__ t1,
                                               const float* __restrict__ bias,
                                               float* __restrict__ x,
                                               const float* __restrict__ gw,
                                               const float* __restrict__ bw,
                                               short* __restrict__ out) {
  const int t = threadIdx.x, w = t >> 6, lane = t & 63;
  const int row = blockIdx.x * 4 + w;
  float4 v[4];
  float s = 0.f, q = 0.f;
#pragma unroll
  for (int i = 0; i < 4; ++i) {
    const int c = (i * 64 + lane) * 4;
    const size_t o = (size_t)row * 1024 + c;
    const float4 xx = *reinterpret_cast<const float4*>(x + o);
    const float4 a  = *reinterpret_cast<const float4*>(t0 + o);
    const float4 b  = *reinterpret_cast<const float4*>(t1 + o);
    const float4 bb = *reinterpret_cast<const float4*>(bias + c);
    float4 r = make_float4(xx.x + a.x + b.x + bb.x, xx.y + a.y + b.y + bb.y,
                           xx.z + a.z + b.z + bb.z, xx.w + a.w + b.w + bb.w);
    *reinterpret_cast<float4*>(x + o) = r;
    v[i] = r;
    s += r.x + r.y + r.z + r.w;
    q += r.x * r.x + r.y * r.y + r.z * r.z + r.w * r.w;
  }
#pragma unroll
  for (int o = 32; o > 0; o >>= 1) { s += __shfl_xor(s, o); q += __shfl_xor(q, o); }
  const float mean = s * (1.f / 1024.f);
  const float var  = q * (1.f / 1024.f) - mean * mean;
  const float rstd = rsqrtf(var + 1e-5f);
#pragma unroll
  for (int i = 0; i < 4; ++i) {
    const int c = (i * 64 + lane) * 4;
    const float4 gv = *reinterpret_cast<const float4*>(gw + c);
    const float4 bv = *reinterpret_cast<const float4*>(bw + c);
    bf16x4 ov = { f2bf((v[i].x - mean) * rstd * gv.x + bv.x),
                  f2bf((v[i].y - mean) * rstd * gv.y + bv.y),
                  f2bf((v[i].z - mean) * rstd * gv.z + bv.z),
                  f2bf((v[i].w - mean) * rstd * gv.w + bv.w) };
    *reinterpret_cast<bf16x4*>(out + (size_t)row * 1024 + c) = ov;
  }
}

// ---------- merged weight transpose+convert: one launch for all 7 weights ----------
struct TSeg {
  const float* src; short* dst;
  unsigned long long inStride, outStride;
  int N, nbx, nbxy, rowOff, ldOut, blkEnd;
  float scale;
};
struct TTab { TSeg s[7]; };

__global__ __launch_bounds__(256) void tcvt_all(TTab tab) {
  const int b = blockIdx.x;
  int si = 0;
  while (b >= tab.s[si].blkEnd) ++si;
  const TSeg sg = tab.s[si];
  const int base = (si == 0) ? 0 : tab.s[si - 1].blkEnd;
  int lb = b - base;
  const int z = lb / sg.nbxy; lb -= z * sg.nbxy;
  const int by = lb / sg.nbx;
  const int bx = lb - by * sg.nbx;

  __shared__ float T[128][68];
  const float* Win = sg.src + (size_t)z * sg.inStride;
  short* Wout = sg.dst + (size_t)z * sg.outStride;
  const int n0 = bx * 64, k0 = by * 128;
  const int t = threadIdx.x;
  const int nc = (t & 15) * 4, kr = t >> 4;
#pragma unroll
  for (int p = 0; p < 8; ++p) {
    const float4 v = *reinterpret_cast<const float4*>(Win + (size_t)(k0 + kr + 16 * p) * sg.N + n0 + nc);
    T[kr + 16 * p][nc + 0] = v.x;
    T[kr + 16 * p][nc + 1] = v.y;
    T[kr + 16 * p][nc + 2] = v.z;
    T[kr + 16 * p][nc + 3] = v.w;
  }
  __syncthreads();
  const int n = t >> 2, ks = (t & 3) * 32;
  short tmp[32];
#pragma unroll
  for (int i = 0; i < 32; ++i) tmp[i] = f2bf(T[ks + i][n] * sg.scale);
  short* op = Wout + (size_t)(sg.rowOff + n0 + n) * sg.ldOut + k0 + ks;
#pragma unroll
  for (int c = 0; c < 4; ++c)
    *reinterpret_cast<bf16x8*>(op + c * 8) = *reinterpret_cast<bf16x8*>(tmp + c * 8);
}

// concat qkv bias (q scaled by 0.125)
__global__ __launch_bounds__(256) void bqkv_k(const float* __restrict__ qb,
                                              const float* __restrict__ kb,
                                              const float* __restrict__ vb,
                                              float* __restrict__ o) {
  int l = blockIdx.y;
  int c = blockIdx.x * 256 + threadIdx.x;
  float v;
  if (c < 1024) v = qb[l * 1024 + c] * 0.125f;
  else if (c < 1280) v = kb[l * 256 + c - 1024];
  else v = vb[l * 256 + c - 1280];
  o[l * 1536 + c] = v;
}

// ---------- V transpose (fallback path only) ----------
__global__ __launch_bounds__(256) void vtr_k(const short* __restrict__ v, int vld,
                                             short* __restrict__ vt) {
  __shared__ short T[64][80];
  const int kvh = blockIdx.y;
  const int s0 = blockIdx.x * 64;
  const int t = threadIdx.x;
  const int row = t >> 3, ch = t & 7;
#pragma unroll
  for (int p = 0; p < 2; ++p) {
    int s = row + 32 * p;
    bf16x8 vv = *reinterpret_cast<const bf16x8*>(v + (size_t)(s0 + s) * vld + kvh * 64 + ch * 8);
    *reinterpret_cast<bf16x8*>(&T[s][ch * 8]) = vv;
  }
  __syncthreads();
#pragma unroll
  for (int p = 0; p < 2; ++p) {
    int d = row + 32 * p;
    short tmp[8];
#pragma unroll
    for (int i = 0; i < 8; ++i) tmp[i] = T[ch * 8 + i][d];
    *reinterpret_cast<bf16x8*>(vt + (size_t)(kvh * 64 + d) * 2048 + s0 + ch * 8) =
        *reinterpret_cast<bf16x8*>(tmp);
  }
}

// ---------- GEMM (m97 structure): C[M,N] = A_bf16[M,K] @ Wt_bf16[N,K]^T ----------
// EPI: 0 bf16 out (acc+bias); 1 bf16 GELU(acc+bias); 2 f32 resid+acc+bias;
//      3 f32 acc (z-slice partial: out + z*M*N); 4 = EPI0 + V^T store to vt
// XSWZ: 0 identity; 1 m-fastest bijective XCD chunking
// TILE: 0 = 128x128; 1 = 128x64
// K is the row stride; [kBeg,kEnd) is the K-range; blockIdx.z shifts the range
// by z*(kEnd-kBeg) (concurrent split-K; EPI3 writes partial at z*M*N).
template <int EPI, int XSWZ, int TILE>
__global__ __launch_bounds__(256, 4)
void gemm_bt(const short* __restrict__ A, const short* __restrict__ Wt,
             const float* __restrict__ bias, const float* __restrict__ resid,
             void* __restrict__ out, int M, int N, int K, int kBeg, int kEnd,
             int nbOff, short* __restrict__ vt) {
  constexpr int BN   = (TILE == 0) ? 128 : 64;
  constexpr int WN   = (TILE == 0) ? 64 : 32;
  constexpr int NT   = (TILE == 0) ? 4 : 2;
  constexpr int BISS = (TILE == 0) ? 4 : 2;
  __shared__ short As[128 * 64];
  __shared__ short Bs[BN * 64];
  const int t = threadIdx.x;
  const int lane = t & 63, w = t >> 6;
  const int g = lane >> 4, r = lane & 15;
  const int wr = w >> 1, wc = w & 1;

  int bx = blockIdx.x, by = blockIdx.y;
  if (XSWZ == 1) {
    const int nbx = gridDim.x, nby = gridDim.y, nwg = nbx * nby;
    const int bid = by * nbx + bx;
    const int q = nwg >> 3, rr = nwg & 7;
    const int xcd = bid & 7, loc = bid >> 3;
    const int sw = (xcd < rr ? xcd * (q + 1) : rr * (q + 1) + (xcd - rr) * q) + loc;
    by = sw % nby; bx = sw / nby;
  }
  const int m0 = by * 128, n0 = (bx + nbOff) * BN;
  const int kShift = (int)blockIdx.z * (kEnd - kBeg);
  const size_t zOfs = (size_t)blockIdx.z * (size_t)M * (size_t)N;

  f32x4 acc[4][NT];
#pragma unroll
  for (int i = 0; i < 4; ++i)
#pragma unroll
    for (int j = 0; j < NT; ++j) { f32x4 z = {0.f, 0.f, 0.f, 0.f}; acc[i][j] = z; }

  const int srow = lane >> 3, sslot = lane & 7;

  for (int k0 = kBeg + kShift; k0 < kEnd + kShift; k0 += 64) {
#pragma unroll
    for (int i = 0; i < 4; ++i) {
      const int rowA = w * 32 + i * 8 + srow;
      const int colA = (sslot ^ (srow & 7)) << 3;
      gload16(A + (size_t)(m0 + rowA) * K + k0 + colA, &As[(w * 32 + i * 8) * 64]);
    }
#pragma unroll
    for (int i = 0; i < BISS; ++i) {
      const int rowB = w * (8 * BISS) + i * 8 + srow;
      const int colB = (sslot ^ (srow & 7)) << 3;
      gload16(Wt + (size_t)(n0 + rowB) * K + k0 + colB, &Bs[(w * (8 * BISS) + i * 8) * 64]);
    }
    __syncthreads();
#pragma unroll
    for (int kk = 0; kk < 64; kk += 32) {
      bf16x8 af[4], bfg[NT];
#pragma unroll
      for (int mt = 0; mt < 4; ++mt)
        af[mt] = *reinterpret_cast<const bf16x8*>(&As[swz(wr * 64 + mt * 16 + r, kk + g * 8)]);
#pragma unroll
      for (int nt = 0; nt < NT; ++nt)
        bfg[nt] = *reinterpret_cast<const bf16x8*>(&Bs[swz(wc * WN + nt * 16 + r, kk + g * 8)]);
#pragma unroll
      for (int mt = 0; mt < 4; ++mt)
#pragma unroll
        for (int nt = 0; nt < NT; ++nt)
          acc[mt][nt] = mfma16(af[mt], bfg[nt], acc[mt][nt]);
    }
    __syncthreads();
  }
#pragma unroll
  for (int nt = 0; nt < NT; ++nt) {
    const int col = n0 + wc * WN + nt * 16 + r;
    const float bv = (EPI == 3) ? 0.f : bias[col];
#pragma unroll
    for (int mt = 0; mt < 4; ++mt) {
      const int rowb = m0 + wr * 64 + mt * 16 + 4 * g;
      short vs[4];
#pragma unroll
      for (int j = 0; j < 4; ++j) {
        const int row = rowb + j;
        const size_t oi = (size_t)row * N + col;
        float vv = acc[mt][nt][j] + bv;
        if (EPI == 0) {
          ((short*)out)[oi] = f2bf(vv);
        } else if (EPI == 1) {
          vv = 0.5f * vv * (1.f + erff(vv * 0.70710678118654752f));
          ((short*)out)[oi] = f2bf(vv);
        } else if (EPI == 2) {
          ((float*)out)[oi] = resid[oi] + vv;
        } else if (EPI == 3) {
          ((float*)out)[oi + zOfs] = vv;
        } else {  // EPI 4
          short bb = f2bf(vv);
          ((short*)out)[oi] = bb;
          vs[j] = bb;
        }
      }
      if (EPI == 4 && col >= 1280) {
        bf16x4 pk = { vs[0], vs[1], vs[2], vs[3] };
        *reinterpret_cast<bf16x4*>(vt + (size_t)(col - 1280) * 2048 + rowb) = pk;
      }
    }
  }
}

// ---------- legacy GEMM (f32 weights) — fallback if ws too small ----------
template <int EPI>
__global__ __launch_bounds__(256)
void gemm_k(const short* __restrict__ A, const float* __restrict__ W,
            const float* __restrict__ bias, const float* resid, void* out,
            int M, int N, int K, float scale) {
  __shared__ short As[128 * 64];
  __shared__ short Bs[128 * 64];
  const int t = threadIdx.x;
  const int lane = t & 63;
  const int g = lane >> 4, r = lane & 15;
  const int wid = t >> 6, wr = wid >> 1, wc = wid & 1;
  const int m0 = blockIdx.y * 128, n0 = blockIdx.x * 128;
  f32x4 acc[4][4];
#pragma unroll
  for (int i = 0; i < 4; ++i)
#pragma unroll
    for (int j = 0; j < 4; ++j) { f32x4 z = {0.f, 0.f, 0.f, 0.f}; acc[i][j] = z; }
  const int arow = t >> 3, ac = t & 7;
  const int bnn = t >> 1, bkh = t & 1;
  for (int k0 = 0; k0 < K; k0 += 64) {
#pragma unroll
    for (int p = 0; p < 4; ++p) {
      int row = arow + 32 * p;
      bf16x8 av = *reinterpret_cast<const bf16x8*>(A + (size_t)(m0 + row) * K + k0 + ac * 8);
      *reinterpret_cast<bf16x8*>(&As[swz(row, ac * 8)]) = av;
    }
#pragma unroll
    for (int p = 0; p < 8; ++p) {
      int kg = 4 * (bkh + 2 * p);
      const float* wp = W + (size_t)(k0 + kg) * N + n0 + bnn;
      bf16x4 wv = { f2bf(wp[0]), f2bf(wp[(size_t)N]), f2bf(wp[(size_t)2 * N]), f2bf(wp[(size_t)3 * N]) };
      *reinterpret_cast<bf16x4*>(&Bs[swz(bnn, kg)]) = wv;
    }
    __syncthreads();
#pragma unroll
    for (int kk = 0; kk < 64; kk += 32) {
      bf16x8 af[4], bfg[4];
#pragma unroll
      for (int mt = 0; mt < 4; ++mt)
        af[mt] = *reinterpret_cast<const bf16x8*>(&As[swz(wr * 64 + mt * 16 + r, kk + g * 8)]);
#pragma unroll
      for (int nt = 0; nt < 4; ++nt)
        bfg[nt] = *reinterpret_cast<const bf16x8*>(&Bs[swz(wc * 64 + nt * 16 + r, kk + g * 8)]);
#pragma unroll
      for (int mt = 0; mt < 4; ++mt)
#pragma unroll
        for (int nt = 0; nt < 4; ++nt)
          acc[mt][nt] = mfma16(af[mt], bfg[nt], acc[mt][nt]);
    }
    __syncthreads();
  }
#pragma unroll
  for (int nt = 0; nt < 4; ++nt) {
    const int col = n0 + wc * 64 + nt * 16 + r;
    const float bv = (EPI == 3) ? 0.f : bias[col];
#pragma unroll
    for (int mt = 0; mt < 4; ++mt) {
#pragma unroll
      for (int j = 0; j < 4; ++j) {
        const int row = m0 + wr * 64 + mt * 16 + 4 * g + j;
        const size_t oi = (size_t)row * N + col;
        float vv = acc[mt][nt][j] + bv;
        if (EPI == 0) {
          ((short*)out)[oi] = f2bf(vv * scale);
        } else if (EPI == 1) {
          vv = 0.5f * vv * (1.f + erff(vv * 0.70710678118654752f));
          ((short*)out)[oi] = f2bf(vv);
        } else if (EPI == 2) {
          ((float*)out)[oi] = resid[oi] + vv;
        } else {
          ((float*)out)[oi] = vv;
        }
      }
    }
  }
}

// ---------- flash-style GQA attention (dbuf, gload_lds staging) ----------
__global__ __launch_bounds__(256) void attn_k(const short* __restrict__ q, int qld,
                                              const short* __restrict__ k, int kld,
                                              const short* __restrict__ vt,
                                              const float* __restrict__ mask,
                                              short* __restrict__ o) {
  __shared__ short Ks[2][64 * 64];  // [s][d], 16B-chunk swizzled
  __shared__ short Vs[2][64 * 64];  // [d][s], 16B-chunk swizzled
  const int t = threadIdx.x, lane = t & 63, w = t >> 6;
  const int g = lane >> 4, r = lane & 15;
  const int h = blockIdx.y, qb = blockIdx.x, kvh = h >> 2;
  const int qrow = qb * 64 + w * 16 + r;

  const short* qp = q + (size_t)qrow * qld + h * 64;
  bf16x8 qf0 = *reinterpret_cast<const bf16x8*>(qp + g * 8);
  bf16x8 qf1 = *reinterpret_cast<const bf16x8*>(qp + 32 + g * 8);

  const short* kbase = k + kvh * 64;                   // + s*kld
  const short* vbase = vt + (size_t)kvh * 64 * 2048;   // + d*2048 + s

  f32x4 oacc[4];
#pragma unroll
  for (int i = 0; i < 4; ++i) { f32x4 z = {0.f, 0.f, 0.f, 0.f}; oacc[i] = z; }
  float m_run = -INFINITY, l_run = 0.f;

  const int srow = w * 8 + (lane >> 3), schunk = lane & 7;

#pragma unroll
  for (int p = 0; p < 2; ++p) {
    const int rr = srow + 32 * p;
    const int cc = (schunk ^ (rr & 7)) << 3;
    gload16(kbase + (size_t)rr * kld + cc, (char*)Ks + p * 4096 + w * 1024);
    gload16(vbase + (size_t)rr * 2048 + cc, (char*)Vs + p * 4096 + w * 1024);
  }
  asm volatile("s_waitcnt vmcnt(0)" ::: "memory");
  __syncthreads();

  for (int it = 0; it < 32; ++it) {
    const int cur = it & 1;
    if (it < 31) {
      const int s1 = (it + 1) * 64;
#pragma unroll
      for (int p = 0; p < 2; ++p) {
        const int rr = srow + 32 * p;
        const int cc = (schunk ^ (rr & 7)) << 3;
        gload16(kbase + (size_t)(s1 + rr) * kld + cc,
                (char*)Ks + (cur ^ 1) * 8192 + p * 4096 + w * 1024);
        gload16(vbase + (size_t)rr * 2048 + s1 + cc,
                (char*)Vs + (cur ^ 1) * 8192 + p * 4096 + w * 1024);
      }
    }
    const int s0 = it * 64;
    const short* Kc = Ks[cur];
    const short* Vc = Vs[cur];

    f32x4 sa[4];
#pragma unroll
    for (int st = 0; st < 4; ++st) {
      bf16x8 kf0 = *reinterpret_cast<const bf16x8*>(&Kc[swz(st * 16 + r, g * 8)]);
      bf16x8 kf1 = *reinterpret_cast<const bf16x8*>(&Kc[swz(st * 16 + r, 32 + g * 8)]);
      f32x4 z = {0.f, 0.f, 0.f, 0.f};
      z = mfma16(kf0, qf0, z);
      z = mfma16(kf1, qf1, z);
      sa[st] = z;
    }
    float sv[16];
    float pmax = -INFINITY;
#pragma unroll
    for (int st = 0; st < 4; ++st) {
      const float4 mv = *reinterpret_cast<const float4*>(mask + s0 + st * 16 + 4 * g);
#pragma unroll
      for (int j = 0; j < 4; ++j) {
        float xx = sa[st][j] + ((const float*)&mv)[j];
        sv[st * 4 + j] = xx;
        pmax = fmaxf(pmax, xx);
      }
    }
    pmax = fmaxf(pmax, __shfl_xor(pmax, 16));
    pmax = fmaxf(pmax, __shfl_xor(pmax, 32));
    float m_new = fmaxf(m_run, pmax);
    float corr = __expf(m_run - m_new);
    float psum = 0.f;
    short pb[16];
#pragma unroll
    for (int i = 0; i < 16; ++i) {
      float p = __expf(sv[i] - m_new);
      psum += p;
      pb[i] = f2bf(p);
    }
    psum += __shfl_xor(psum, 16);
    psum += __shfl_xor(psum, 32);
    l_run = l_run * corr + psum;
    m_run = m_new;
#pragma unroll
    for (int dt = 0; dt < 4; ++dt)
#pragma unroll
      for (int j = 0; j < 4; ++j) oacc[dt][j] *= corr;

#pragma unroll
    for (int hs = 0; hs < 2; ++hs) {
      bf16x8 pf = { pb[hs * 8 + 0], pb[hs * 8 + 1], pb[hs * 8 + 2], pb[hs * 8 + 3],
                    pb[hs * 8 + 4], pb[hs * 8 + 5], pb[hs * 8 + 6], pb[hs * 8 + 7] };
#pragma unroll
      for (int dt = 0; dt < 4; ++dt) {
        int d = dt * 16 + r;
        int c1 = 4 * g + 32 * hs;
        bf16x4 va  = *reinterpret_cast<const bf16x4*>(&Vc[swz(d, c1)]);
        bf16x4 vb2 = *reinterpret_cast<const bf16x4*>(&Vc[swz(d, c1 + 16)]);
        bf16x8 vf = { va[0], va[1], va[2], va[3], vb2[0], vb2[1], vb2[2], vb2[3] };
        oacc[dt] = mfma16(vf, pf, oacc[dt]);
      }
    }
    asm volatile("s_waitcnt vmcnt(0)" ::: "memory");
    __syncthreads();
  }
  float inv = 1.f / l_run;
#pragma unroll
  for (int dt = 0; dt < 4; ++dt) {
    bf16x4 ov = { f2bf(oacc[dt][0] * inv), f2bf(oacc[dt][1] * inv),
                  f2bf(oacc[dt][2] * inv), f2bf(oacc[dt][3] * inv) };
    *reinterpret_cast<bf16x4*>(o + (size_t)qrow * 1024 + h * 64 + dt * 16 + 4 * g) = ov;
  }
}

// ---------- launch ----------
extern "C" void kernel_launch(void* const* d_in, const int* in_sizes, int n_in,
                              void* d_out, int out_size, void* d_ws, size_t ws_size,
                              hipStream_t stream) {
  const int*   ids   = (const int*)d_in[0];
  const float* mask  = (const float*)d_in[1];
  const float* tok   = (const float*)d_in[2];
  const float* pos   = (const float*)d_in[3];
  const float* qW    = (const float*)d_in[4];
  const float* qbias = (const float*)d_in[5];
  const float* kW    = (const float*)d_in[6];
  const float* kbias = (const float*)d_in[7];
  const float* vW    = (const float*)d_in[8];
  const float* vbias = (const float*)d_in[9];
  const float* oW    = (const float*)d_in[10];
  const float* obias = (const float*)d_in[11];
  const float* m1W   = (const float*)d_in[12];
  const float* m1b   = (const float*)d_in[13];
  const float* m2W   = (const float*)d_in[14];
  const float* m2b   = (const float*)d_in[15];
  const float* ln1g  = (const float*)d_in[16];
  const float* ln1b  = (const float*)d_in[17];
  const float* ln2g  = (const float*)d_in[18];
  const float* ln2b  = (const float*)d_in[19];
  const float* lnfg  = (const float*)d_in[20];
  const float* lnfb  = (const float*)d_in[21];
  const float* headW = (const float*)d_in[22];
  float* out = (float*)d_out;

  char* ws = (char*)d_ws;
  float* x   = (float*)ws;                        // 8 MB
  short* xb  = (short*)(ws + 8388608ull);         // 4 MB

  const size_t OFF_QKV  = 12582912ull;   // 6 MB  bf16 [2048][1536]
  const size_t OFF_AO   = 18874368ull;   // 4 MB
  const size_t OFF_FF   = 23068672ull;   // 16 MB (first 1 MB aliased as vt)
  const size_t OFF_BQ   = 39845888ull;   // 24 KB f32 [4][1536]
  const size_t OFF_WQKV = 39870464ull;   // 12 MB bf16 [4][1536][1024]
  const size_t OFF_WO   = 52453376ull;   // 8 MB  bf16 [4][1024][1024]
  const size_t OFF_WM1  = 60841984ull;   // 32 MB bf16 [4][4096][1024]
  const size_t OFF_WM2  = 94396416ull;   // 32 MB bf16 [4][1024][4096]
  const size_t OFF_WH   = 127950848ull;  // 64 MB bf16 [32000][1024]
  const size_t OFF_TMP  = 193486848ull;  // 16 MB f32 [2][2048][1024] split-K partials
  const size_t NEED     = 210264064ull;

  if (ws_size >= NEED) {
    short* qkv  = (short*)(ws + OFF_QKV);
    short* ao   = (short*)(ws + OFF_AO);
    short* ff   = (short*)(ws + OFF_FF);
    short* vt   = ff;  // alias: ff dead during QKV->attn window
    float* bqv  = (float*)(ws + OFF_BQ);
    short* Wqkv = (short*)(ws + OFF_WQKV);
    short* Wo   = (short*)(ws + OFF_WO);
    short* Wm1  = (short*)(ws + OFF_WM1);
    short* Wm2  = (short*)(ws + OFF_WM2);
    short* Wh   = (short*)(ws + OFF_WH);
    float* tmp0 = (float*)(ws + OFF_TMP);
    float* tmp1 = tmp0 + 2097152;  // 2048*1024

    // ---- merged weight conversion (one launch) ----
    TTab tab;
    int acc = 0;
    auto seg = [&](int i, const float* src, short* dst, size_t inS, size_t outS,
                   int N, int nbx, int nby, int nbz, int rowOff, int ldOut, float scale) {
      acc += nbx * nby * nbz;
      tab.s[i].src = src;      tab.s[i].dst = dst;
      tab.s[i].inStride = inS; tab.s[i].outStride = outS;
      tab.s[i].N = N;          tab.s[i].nbx = nbx;
      tab.s[i].nbxy = nbx * nby;
      tab.s[i].rowOff = rowOff; tab.s[i].ldOut = ldOut;
      tab.s[i].blkEnd = acc;   tab.s[i].scale = scale;
    };
    seg(0, headW, Wh,   0ull,        0ull,        32000, 500, 8, 1, 0,    1024, 1.f);
    seg(1, m1W,   Wm1,  4194304ull,  4194304ull,  4096,  64,  8, 4, 0,    1024, 1.f);
    seg(2, m2W,   Wm2,  4194304ull,  4194304ull,  1024,  16, 32, 4, 0,    4096, 1.f);
    seg(3, qW,    Wqkv, 1048576ull,  1572864ull,  1024,  16,  8, 4, 0,    1024, 0.125f);
    seg(4, oW,    Wo,   1048576ull,  1048576ull,  1024,  16,  8, 4, 0,    1024, 1.f);
    seg(5, kW,    Wqkv, 262144ull,   1572864ull,  256,   4,   8, 4, 1024, 1024, 1.f);
    seg(6, vW,    Wqkv, 262144ull,   1572864ull,  256,   4,   8, 4, 1280, 1024, 1.f);
    tcvt_all<<<acc, 256, 0, stream>>>(tab);
    bqkv_k<<<dim3(6, 4), 256, 0, stream>>>(qbias, kbias, vbias, bqv);

    embed_k<<<512, 256, 0, stream>>>(ids, tok, pos, x);

    for (int l = 0; l < 4; ++l) {
      short* Wq_l  = Wqkv + (size_t)l * 1536 * 1024;
      short* Wo_l  = Wo   + (size_t)l * 1024 * 1024;
      short* Wm1_l = Wm1  + (size_t)l * 4096 * 1024;
      short* Wm2_l = Wm2  + (size_t)l * 1024 * 4096;

      // LN1 (layers 1..3: fused with previous layer's m2 split-K combine)
      if (l == 0) {
        ln_k<<<512, 256, 0, stream>>>(x, ln1g, ln1b, xb);
      } else {
        comb_ln<<<512, 256, 0, stream>>>(tmp0, tmp1, m2b + (l - 1) * 1024, x,
                                         ln1g + l * 1024, ln1b + l * 1024, xb);
      }
      gemm_bt<4, 0, 1><<<dim3(24, 16), 256, 0, stream>>>(xb, Wq_l, bqv + l * 1536, nullptr,
                                                         qkv, 2048, 1536, 1024, 0, 1024, 0, vt);
      attn_k<<<dim3(32, 16), 256, 0, stream>>>(qkv, 1536, qkv + 1024, 1536, vt, mask, ao);
      // o-proj: concurrent split-K x2 -> partials; combine fused into LN2.
      gemm_bt<3, 1, 1><<<dim3(16, 16, 2), 256, 0, stream>>>(ao, Wo_l, nullptr, nullptr,
                                                            tmp0, 2048, 1024, 1024, 0, 512, 0, nullptr);
      comb_ln<<<512, 256, 0, stream>>>(tmp0, tmp1, obias + l * 1024, x,
                                       ln2g + l * 1024, ln2b + l * 1024, xb);
      gemm_bt<1, 1, 1><<<dim3(64, 16), 256, 0, stream>>>(xb, Wm1_l, m1b + l * 4096, nullptr,
                                                         ff, 2048, 4096, 1024, 0, 1024, 0, nullptr);
      // m2: concurrent split-K x2 -> partials; combine fused into next LN1 / final LNf.
      gemm_bt<3, 1, 1><<<dim3(16, 16, 2), 256, 0, stream>>>(ff, Wm2_l, nullptr, nullptr,
                                                            tmp0, 2048, 1024, 4096, 0, 2048, 0, nullptr);
    }
    comb_ln<<<512, 256, 0, stream>>>(tmp0, tmp1, m2b + 3 * 1024, x, lnfg, lnfb, xb);
    gemm_bt<3, 1, 0><<<dim3(250, 16), 256, 0, stream>>>(xb, Wh, nullptr, nullptr,
                                                        out, 2048, 32000, 1024, 0, 1024, 0, nullptr);
  } else {
    // fallback: f32-weight GEMMs, needs < 40 MB ws
    short* qbf = (short*)(ws + (12u << 20));
    short* kbf = (short*)(ws + (16u << 20));
    short* vbf = (short*)(ws + (17u << 20));
    short* ao  = (short*)(ws + (18u << 20));
    short* ff  = (short*)(ws + (22u << 20));
    short* vtf = (short*)(ws + (38u << 20));

    embed_k<<<512, 256, 0, stream>>>(ids, tok, pos, x);
    for (int l = 0; l < 4; ++l) {
      ln_k<<<512, 256, 0, stream>>>(x, ln1g + l * 1024, ln1b + l * 1024, xb);
      gemm_k<0><<<dim3(8, 16), 256, 0, stream>>>(xb, qW + (size_t)l * 1024 * 1024,
          qbias + l * 1024, nullptr, qbf, 2048, 1024, 1024, 0.125f);
      gemm_k<0><<<dim3(2, 16), 256, 0, stream>>>(xb, kW + (size_t)l * 1024 * 256,
          kbias + l * 256, nullptr, kbf, 2048, 256, 1024, 1.f);
      gemm_k<0><<<dim3(2, 16), 256, 0, stream>>>(xb, vW + (size_t)l * 1024 * 256,
          vbias + l * 256, nullptr, vbf, 2048, 256, 1024, 1.f);
      vtr_k<<<dim3(32, 4), 256, 0, stream>>>(vbf, 256, vtf);
      attn_k<<<dim3(32, 16), 256, 0, stream>>>(qbf, 1024, kbf, 256, vtf, mask, ao);
      gemm_k<2><<<dim3(8, 16), 256, 0, stream>>>(ao, oW + (size_t)l * 1024 * 1024,
          obias + l * 1024, x, x, 2048, 1024, 1024, 1.f);
      ln_k<<<512, 256, 0, stream>>>(x, ln2g + l * 1024, ln2b + l * 1024, xb);
      gemm_k<1><<<dim3(32, 16), 256, 0, stream>>>(xb, m1W + (size_t)l * 1024 * 4096,
          m1b + l * 4096, nullptr, ff, 2048, 4096, 1024, 1.f);
      gemm_k<2><<<dim3(8, 16), 256, 0, stream>>>(ff, m2W + (size_t)l * 4096 * 1024,
          m2b + l * 1024, x, x, 2048, 1024, 4096, 1.f);
    }
    ln_k<<<512, 256, 0, stream>>>(x, lnfg, lnfb, xb);
    gemm_k<3><<<dim3(250, 16), 256, 0, stream>>>(xb, headW, nullptr, nullptr, out,
        2048, 32000, 1024, 1.f);
  }
}